// Round 3
// baseline (642.742 us; speedup 1.0000x reference)
//
#include <hip/hip_runtime.h>

constexpr int Nn    = 20000;
constexpr int Ee    = 320000;
constexpr int Dd    = 1280;
constexpr int Gg    = 256;
constexpr int ETOT  = Ee + Nn;
#define NEG 0.2f

typedef __attribute__((ext_vector_type(8))) short s8v;     // 8 bf16 = 4 VGPR
typedef __attribute__((ext_vector_type(4))) float f4v;     // MFMA acc

__device__ inline float lrelu(float v){ return v > 0.f ? v : NEG * v; }
__device__ inline float wave_sum(float v){
  #pragma unroll
  for(int o = 32; o; o >>= 1) v += __shfl_xor(v, o, 64);
  return v;
}
__device__ inline unsigned short f2bf(float x){
  unsigned u = __float_as_uint(x);
  return (unsigned short)((u + 0x7FFFu + ((u >> 16) & 1u)) >> 16);   // RNE
}
__device__ inline float bf2f(unsigned short h){ return __uint_as_float(((unsigned)h) << 16); }

__device__ inline void async_cp16(const void* g, void* l){
  __builtin_amdgcn_global_load_lds((const __attribute__((address_space(1))) void*)g,
                                   (__attribute__((address_space(3))) void*)l, 16, 0, 0);
}

// ---------------- CSR build (by destination) ----------------
__global__ void fill_int(int* p, int n, int v){
  int i = blockIdx.x * blockDim.x + threadIdx.x;
  if(i < n) p[i] = v;
}
__global__ void zero_float(float* p, int n){
  int i = blockIdx.x * blockDim.x + threadIdx.x;
  if(i < n) p[i] = 0.f;
}
__global__ void hist_dst(const int* __restrict__ dst, int* __restrict__ deg){
  int e = blockIdx.x * blockDim.x + threadIdx.x;
  if(e < Ee) atomicAdd(&deg[dst[e]], 1);
}
__global__ __launch_bounds__(1024) void scan_deg(const int* __restrict__ deg,
                                                 int* __restrict__ rowptr,
                                                 int* __restrict__ cursor){
  __shared__ int part[1024];
  int t = threadIdx.x;
  const int CH = (Nn + 1023) / 1024;
  int base = t * CH;
  int s = 0;
  for(int j = 0; j < CH; j++){ int idx = base + j; if(idx < Nn) s += deg[idx]; }
  part[t] = s;
  __syncthreads();
  for(int off = 1; off < 1024; off <<= 1){
    int v = (t >= off) ? part[t - off] : 0;
    __syncthreads();
    part[t] += v;
    __syncthreads();
  }
  int acc = part[t] - s;
  for(int j = 0; j < CH; j++){
    int idx = base + j;
    if(idx < Nn){ rowptr[idx] = acc; cursor[idx] = acc; acc += deg[idx]; }
  }
  if(t == 1023) rowptr[Nn] = part[1023];
}
__global__ void scatter_edges(const int* __restrict__ dst, int* __restrict__ cursor,
                              int* __restrict__ eid){
  int e = blockIdx.x * blockDim.x + threadIdx.x;
  if(e >= ETOT) return;
  int d = (e < Ee) ? dst[e] : (e - Ee);
  int pos = atomicAdd(&cursor[d], 1);
  eid[pos] = e;
}

// ------------- W^T split: [2*Ca][K] bf16 hi/lo from Wl|Wr [K][Ca] -------------
__global__ __launch_bounds__(256) void wsplit(const float* __restrict__ Wl,
                                              const float* __restrict__ Wr,
                                              int K, int Ca,
                                              unsigned short* __restrict__ WTH,
                                              unsigned short* __restrict__ WTL){
  __shared__ float t[32][33];
  int k0 = blockIdx.x * 32, n0 = blockIdx.y * 32;
  int tx = threadIdx.x & 31, ty = threadIdx.x >> 5;
  #pragma unroll
  for(int j = 0; j < 4; j++){
    int kk = ty + j * 8;
    int n = n0 + tx;
    t[kk][tx] = (n < Ca) ? Wl[(size_t)(k0 + kk) * Ca + n]
                         : Wr[(size_t)(k0 + kk) * Ca + (n - Ca)];
  }
  __syncthreads();
  #pragma unroll
  for(int j = 0; j < 4; j++){
    int nn = ty + j * 8;
    float v = t[tx][nn];
    unsigned short hi = f2bf(v);
    unsigned short lo = f2bf(v - bf2f(hi));
    WTH[(size_t)(n0 + nn) * K + k0 + tx] = hi;
    WTL[(size_t)(n0 + nn) * K + k0 + tx] = lo;
  }
}

// ------------- split-bf16 MFMA GEMM (2-term): Y = X @ WT^T + bias -------------
// tile M=64 (blockIdx.y) x N=128 (blockIdx.x), BK=32, double-buffered, 1 barrier/iter.
// LDS layout [kchunk g(4)][row][8] -> contiguous 16B chunks per quad (conflict-free).
__global__ __launch_bounds__(256) void gemm_mfma_2t(
    const float* __restrict__ X, int K, int niter,
    const unsigned short* __restrict__ WTH, const unsigned short* __restrict__ WTL,
    const float* __restrict__ bl, const float* __restrict__ br, int Ca,
    float* __restrict__ Ya, float* __restrict__ Yb)
{
  __shared__ unsigned short sA [2][64 * 32];    // 8 KB
  __shared__ unsigned short sBh[2][128 * 32];   // 16 KB
  __shared__ unsigned short sBl[2][128 * 32];   // 16 KB

  const int tid = threadIdx.x;
  const int lane = tid & 63;
  const int w = tid >> 6;
  const int wm = w & 1, wn = w >> 1;
  const int bm = blockIdx.y * 64;
  const int bn = blockIdx.x * 128;

  f4v acc[2][4] = {};

  // A staging map (2 float4 per thread): row = idx>>3 (0..63), seg = idx&7
  int arow[2], aseg[2];
  const float* aptr[2];
  #pragma unroll
  for(int r = 0; r < 2; r++){
    int idx = r * 256 + tid;
    arow[r] = idx >> 3; aseg[r] = idx & 7;
    int gm = bm + arow[r]; if(gm >= Nn) gm = Nn - 1;
    aptr[r] = X + (size_t)gm * K + aseg[r] * 4;
  }
  // B chunk decode: chunk c = r*256 + w*64 + lane; g = c>>7, nrow = c&127
  int bg[2], bnrow[2];
  #pragma unroll
  for(int r = 0; r < 2; r++){
    int c = r * 256 + w * 64 + lane;
    bg[r] = c >> 7; bnrow[r] = c & 127;
  }

  // prologue: stage iter 0 into buf 0
  #pragma unroll
  for(int r = 0; r < 2; r++){
    const unsigned short* gh = WTH + (size_t)(bn + bnrow[r]) * K + bg[r] * 8;
    const unsigned short* gl = WTL + (size_t)(bn + bnrow[r]) * K + bg[r] * 8;
    async_cp16(gh, &sBh[0][(r * 256 + w * 64) * 8]);
    async_cp16(gl, &sBl[0][(r * 256 + w * 64) * 8]);
  }
  #pragma unroll
  for(int r = 0; r < 2; r++){
    float4 v = *(const float4*)(aptr[r]);
    ushort4 h = make_ushort4(f2bf(v.x), f2bf(v.y), f2bf(v.z), f2bf(v.w));
    *(ushort4*)&sA[0][((aseg[r] >> 1) * 64 + arow[r]) * 8 + (aseg[r] & 1) * 4] = h;
  }

  const int mr = lane & 15;
  const int g  = lane >> 4;

  for(int it = 0; it < niter; it++){
    int cur = it & 1, nxt = cur ^ 1;
    __syncthreads();                       // buf[cur] ready (barrier drains vm+lgkm)
    float4 av[2];
    if(it + 1 < niter){
      int k0n = (it + 1) * 32;
      #pragma unroll
      for(int r = 0; r < 2; r++){
        const unsigned short* gh = WTH + (size_t)(bn + bnrow[r]) * K + k0n + bg[r] * 8;
        const unsigned short* gl = WTL + (size_t)(bn + bnrow[r]) * K + k0n + bg[r] * 8;
        async_cp16(gh, &sBh[nxt][(r * 256 + w * 64) * 8]);
        async_cp16(gl, &sBl[nxt][(r * 256 + w * 64) * 8]);
      }
      #pragma unroll
      for(int r = 0; r < 2; r++) av[r] = *(const float4*)(aptr[r] + k0n);
    }
    s8v ah[2];
    #pragma unroll
    for(int i = 0; i < 2; i++){
      int row = wm * 32 + i * 16 + mr;
      ah[i] = *(const s8v*)&sA[cur][(g * 64 + row) * 8];
    }
    #pragma unroll
    for(int j = 0; j < 4; j++){
      int row = wn * 64 + j * 16 + mr;
      s8v bh  = *(const s8v*)&sBh[cur][(g * 128 + row) * 8];
      s8v bl2 = *(const s8v*)&sBl[cur][(g * 128 + row) * 8];
      #pragma unroll
      for(int i = 0; i < 2; i++){
        acc[i][j] = __builtin_amdgcn_mfma_f32_16x16x32_bf16(ah[i], bh,  acc[i][j], 0, 0, 0);
        acc[i][j] = __builtin_amdgcn_mfma_f32_16x16x32_bf16(ah[i], bl2, acc[i][j], 0, 0, 0);
      }
    }
    if(it + 1 < niter){
      #pragma unroll
      for(int r = 0; r < 2; r++){
        ushort4 h = make_ushort4(f2bf(av[r].x), f2bf(av[r].y), f2bf(av[r].z), f2bf(av[r].w));
        *(ushort4*)&sA[nxt][((aseg[r] >> 1) * 64 + arow[r]) * 8 + (aseg[r] & 1) * 4] = h;
      }
    }
  }

  // epilogue: C/D map col=lane&15, row=(lane>>4)*4+reg
  const int quad = lane >> 4, col = lane & 15;
  #pragma unroll
  for(int j = 0; j < 4; j++){
    int gn = bn + wn * 64 + j * 16 + col;
    const float* bias = (gn < Ca) ? bl : br;
    float*       Y    = (gn < Ca) ? Ya : Yb;
    int cn = gn & (Ca - 1);                // Ca is a power of two (256 / 64)
    float bv = bias[cn];
    #pragma unroll
    for(int i = 0; i < 2; i++){
      #pragma unroll
      for(int rg = 0; rg < 4; rg++){
        int gm = bm + wm * 32 + i * 16 + quad * 4 + rg;
        if(gm < Nn) Y[(size_t)gm * Ca + cn] = acc[i][j][rg] + bv;
      }
    }
  }
}

// -------- fused GATv2 layer 1: wave/node, 4 independent online-softmax chains --------
__global__ __launch_bounds__(256) void gat_fused1(
    const int* __restrict__ rowptr, const int* __restrict__ eid,
    const int* __restrict__ src,
    const float* __restrict__ XL, const float* __restrict__ XR,
    const float* __restrict__ att, const float* __restrict__ bias,
    float* __restrict__ H)
{
  int node = blockIdx.x * 4 + (threadIdx.x >> 6);
  int lane = threadIdx.x & 63;
  if(node >= Nn) return;
  const float4 xr = *(const float4*)(XR + (size_t)node * 256 + lane * 4);
  const float4 a  = *(const float4*)(att + lane * 4);
  int r0 = rowptr[node], r1 = rowptr[node + 1];
  float m[4], l[4]; float4 acc[4];
  #pragma unroll
  for(int c = 0; c < 4; c++){ m[c] = -1e30f; l[c] = 0.f; acc[c] = make_float4(0,0,0,0); }
  for(int k = r0; k < r1; k += 4){
    int nv = r1 - k;                       // wave-uniform
    int s[4]; float4 xl[4]; float p[4];
    #pragma unroll
    for(int c = 0; c < 4; c++){
      int kk = (c < nv) ? (k + c) : k;
      int e = eid[kk];
      s[c] = (e < Ee) ? src[e] : node;
    }
    #pragma unroll
    for(int c = 0; c < 4; c++) xl[c] = *(const float4*)(XL + (size_t)s[c] * 256 + lane * 4);
    #pragma unroll
    for(int c = 0; c < 4; c++){
      p[c] = lrelu(xl[c].x + xr.x) * a.x + lrelu(xl[c].y + xr.y) * a.y
           + lrelu(xl[c].z + xr.z) * a.z + lrelu(xl[c].w + xr.w) * a.w;
    }
    #pragma unroll
    for(int o = 8; o; o >>= 1){
      #pragma unroll
      for(int c = 0; c < 4; c++) p[c] += __shfl_xor(p[c], o, 64);
    }
    #pragma unroll
    for(int c = 0; c < 4; c++){
      if(c < nv){
        float mn = fmaxf(m[c], p[c]);
        float sc = __expf(m[c] - mn);
        float wg = __expf(p[c] - mn);
        l[c] = l[c] * sc + wg;
        acc[c].x = acc[c].x * sc + wg * xl[c].x;
        acc[c].y = acc[c].y * sc + wg * xl[c].y;
        acc[c].z = acc[c].z * sc + wg * xl[c].z;
        acc[c].w = acc[c].w * sc + wg * xl[c].w;
        m[c] = mn;
      }
    }
  }
  float M = fmaxf(fmaxf(m[0], m[1]), fmaxf(m[2], m[3]));
  float L = 0.f; float4 A4 = make_float4(0,0,0,0);
  #pragma unroll
  for(int c = 0; c < 4; c++){
    float sc = __expf(m[c] - M);
    L += l[c] * sc;
    A4.x += acc[c].x * sc; A4.y += acc[c].y * sc;
    A4.z += acc[c].z * sc; A4.w += acc[c].w * sc;
  }
  float inv = 1.f / (L + 1e-16f);
  const float4 b = *(const float4*)(bias + lane * 4);
  float4 o;
  o.x = fmaxf(A4.x * inv + b.x, 0.f);
  o.y = fmaxf(A4.y * inv + b.y, 0.f);
  o.z = fmaxf(A4.z * inv + b.z, 0.f);
  o.w = fmaxf(A4.w * inv + b.w, 0.f);
  *(float4*)(H + (size_t)node * 256 + lane * 4) = o;
}

// -------- fused GATv2 layer 2: wave/node, heads=1, 64 ch, 4 chains --------
__global__ __launch_bounds__(256) void gat_fused2(
    const int* __restrict__ rowptr, const int* __restrict__ eid,
    const int* __restrict__ src,
    const float* __restrict__ XL, const float* __restrict__ XR,
    const float* __restrict__ att, const float* __restrict__ bias,
    float* __restrict__ H)
{
  int node = blockIdx.x * 4 + (threadIdx.x >> 6);
  int lane = threadIdx.x & 63;
  if(node >= Nn) return;
  const float xr = XR[(size_t)node * 64 + lane];
  const float a = att[lane];
  int r0 = rowptr[node], r1 = rowptr[node + 1];
  float m[4], l[4], acc[4];
  #pragma unroll
  for(int c = 0; c < 4; c++){ m[c] = -1e30f; l[c] = 0.f; acc[c] = 0.f; }
  for(int k = r0; k < r1; k += 4){
    int nv = r1 - k;
    int s[4]; float xl[4]; float p[4];
    #pragma unroll
    for(int c = 0; c < 4; c++){
      int kk = (c < nv) ? (k + c) : k;
      int e = eid[kk];
      s[c] = (e < Ee) ? src[e] : node;
    }
    #pragma unroll
    for(int c = 0; c < 4; c++) xl[c] = XL[(size_t)s[c] * 64 + lane];
    #pragma unroll
    for(int c = 0; c < 4; c++) p[c] = lrelu(xl[c] + xr) * a;
    #pragma unroll
    for(int o = 32; o; o >>= 1){
      #pragma unroll
      for(int c = 0; c < 4; c++) p[c] += __shfl_xor(p[c], o, 64);
    }
    #pragma unroll
    for(int c = 0; c < 4; c++){
      if(c < nv){
        float mn = fmaxf(m[c], p[c]);
        float sc = __expf(m[c] - mn);
        float wg = __expf(p[c] - mn);
        l[c] = l[c] * sc + wg;
        acc[c] = acc[c] * sc + wg * xl[c];
        m[c] = mn;
      }
    }
  }
  float M = fmaxf(fmaxf(m[0], m[1]), fmaxf(m[2], m[3]));
  float L = 0.f, A1 = 0.f;
  #pragma unroll
  for(int c = 0; c < 4; c++){
    float sc = __expf(m[c] - M);
    L += l[c] * sc; A1 += acc[c] * sc;
  }
  float inv = 1.f / (L + 1e-16f);
  H[(size_t)node * 64 + lane] = fmaxf(A1 * inv + bias[lane], 0.f);
}

// ---------------- pool + MLP head ----------------
__global__ void pool_kernel(const float* __restrict__ H2, const int* __restrict__ batch,
                            float* __restrict__ GP){
  int gid = blockIdx.x * blockDim.x + threadIdx.x;
  if(gid >= Nn * 16) return;
  int i = gid >> 4;
  int c = (gid & 15) * 4;
  int b = batch[i];
  const float4 v = *(const float4*)(H2 + (size_t)i * 64 + c);
  atomicAdd(&GP[b * 64 + c + 0], v.x);
  atomicAdd(&GP[b * 64 + c + 1], v.y);
  atomicAdd(&GP[b * 64 + c + 2], v.z);
  atomicAdd(&GP[b * 64 + c + 3], v.w);
}
__global__ __launch_bounds__(64) void mlp_head(const float* __restrict__ GP,
                                               const float* __restrict__ W3,
                                               const float* __restrict__ b3,
                                               const float* __restrict__ W4,
                                               const float* __restrict__ b4,
                                               float* __restrict__ out){
  int g = blockIdx.x;
  int j = threadIdx.x;
  __shared__ float sh[64];
  sh[j] = GP[(size_t)g * 64 + j];
  __syncthreads();
  float t = b3[j];
  #pragma unroll
  for(int k = 0; k < 64; k++) t = fmaf(sh[k], W3[k * 64 + j], t);
  t = fmaxf(t, 0.f);
  float p = t * W4[j];
  p = wave_sum(p);
  if(j == 0) out[g] = p + b4[0];
}

extern "C" void kernel_launch(void* const* d_in, const int* in_sizes, int n_in,
                              void* d_out, int out_size, void* d_ws, size_t ws_size,
                              hipStream_t stream)
{
  const float* x     = (const float*)d_in[0];
  const int*   ei    = (const int*)d_in[1];
  const int*   batch = (const int*)d_in[2];
  const float* Wl1   = (const float*)d_in[3];
  const float* bl1   = (const float*)d_in[4];
  const float* Wr1   = (const float*)d_in[5];
  const float* br1   = (const float*)d_in[6];
  const float* att1  = (const float*)d_in[7];
  const float* bias1 = (const float*)d_in[8];
  const float* Wl2   = (const float*)d_in[9];
  const float* bl2   = (const float*)d_in[10];
  const float* Wr2   = (const float*)d_in[11];
  const float* br2   = (const float*)d_in[12];
  const float* att2  = (const float*)d_in[13];
  const float* bias2 = (const float*)d_in[14];
  const float* W3    = (const float*)d_in[15];
  const float* b3    = (const float*)d_in[16];
  const float* W4    = (const float*)d_in[17];
  const float* b4    = (const float*)d_in[18];
  float* out = (float*)d_out;

  char* ws = (char*)d_ws;
  size_t off = 0;
  auto alloc = [&](size_t bytes) -> void* {
    void* p = ws + off;
    off += (bytes + 255) & ~(size_t)255;
    return p;
  };
  float* XL1  = (float*)alloc((size_t)Nn * 256 * 4);   // reused as XL2
  float* XR1  = (float*)alloc((size_t)Nn * 256 * 4);   // reused as XR2
  float* H1   = (float*)alloc((size_t)Nn * 256 * 4);
  unsigned short* WTH  = (unsigned short*)alloc((size_t)512 * Dd * 2);
  unsigned short* WTL  = (unsigned short*)alloc((size_t)512 * Dd * 2);
  unsigned short* WT2H = (unsigned short*)alloc((size_t)128 * 256 * 2);
  unsigned short* WT2L = (unsigned short*)alloc((size_t)128 * 256 * 2);
  int*   rowptr = (int*)alloc((size_t)(Nn + 1) * 4);
  int*   deg    = (int*)alloc((size_t)Nn * 4);
  int*   cursor = (int*)alloc((size_t)Nn * 4);
  int*   eid    = (int*)alloc((size_t)ETOT * 4);
  float* H2   = (float*)alloc((size_t)Nn * 64 * 4);
  float* GP   = (float*)alloc((size_t)Gg * 64 * 4);
  float* XL2 = XL1;
  float* XR2 = XR1;

  const int* srcA = ei;
  const int* dstA = ei + Ee;

  // CSR by destination (self-loop folded in via deg init = 1)
  fill_int<<<(Nn + 255) / 256, 256, 0, stream>>>(deg, Nn, 1);
  hist_dst<<<(Ee + 255) / 256, 256, 0, stream>>>(dstA, deg);
  scan_deg<<<1, 1024, 0, stream>>>(deg, rowptr, cursor);
  scatter_edges<<<(ETOT + 255) / 256, 256, 0, stream>>>(dstA, cursor, eid);

  // weight transposes + bf16 hi/lo splits
  wsplit<<<dim3(Dd / 32, 512 / 32), 256, 0, stream>>>(Wl1, Wr1, Dd, 256, WTH, WTL);
  wsplit<<<dim3(256 / 32, 128 / 32), 256, 0, stream>>>(Wl2, Wr2, 256, 64, WT2H, WT2L);

  // layer 1: X[20000x1280] @ WT^T -> XL1|XR1 [20000x256 each]
  gemm_mfma_2t<<<dim3(4, (Nn + 63) / 64), 256, 0, stream>>>(
      x, Dd, Dd / 32, WTH, WTL, bl1, br1, 256, XL1, XR1);
  gat_fused1<<<(Nn + 3) / 4, 256, 0, stream>>>(rowptr, eid, srcA, XL1, XR1, att1, bias1, H1);

  // layer 2: H1[20000x256] @ WT2^T -> XL2|XR2 [20000x64 each]
  gemm_mfma_2t<<<dim3(1, (Nn + 63) / 64), 256, 0, stream>>>(
      H1, 256, 256 / 32, WT2H, WT2L, bl2, br2, 64, XL2, XR2);
  gat_fused2<<<(Nn + 3) / 4, 256, 0, stream>>>(rowptr, eid, srcA, XL2, XR2, att2, bias2, H2);

  // pool + head
  zero_float<<<(Gg * 64 + 255) / 256, 256, 0, stream>>>(GP, Gg * 64);
  pool_kernel<<<(Nn * 16 + 255) / 256, 256, 0, stream>>>(H2, batch, GP);
  mlp_head<<<Gg, 64, 0, stream>>>(GP, W3, b3, W4, b4, out);
}

// Round 4
// 549.434 us; speedup vs baseline: 1.1698x; 1.1698x over previous
//
#include <hip/hip_runtime.h>

constexpr int Nn    = 20000;
constexpr int Ee    = 320000;
constexpr int Dd    = 1280;
constexpr int Gg    = 256;
constexpr int ETOT  = Ee + Nn;
#define NEG 0.2f

typedef __attribute__((ext_vector_type(8))) short s8v;            // 8 bf16 = 4 VGPR
typedef __attribute__((ext_vector_type(8))) unsigned short u16x8;
typedef __attribute__((ext_vector_type(4))) float f4v;            // MFMA acc

__device__ inline float lrelu(float v){ return v > 0.f ? v : NEG * v; }
__device__ inline float wave_sum(float v){
  #pragma unroll
  for(int o = 32; o; o >>= 1) v += __shfl_xor(v, o, 64);
  return v;
}
__device__ inline unsigned short f2bf(float x){
  unsigned u = __float_as_uint(x);
  return (unsigned short)((u + 0x7FFFu + ((u >> 16) & 1u)) >> 16);   // RNE
}
__device__ inline float bf2f(unsigned short h){ return __uint_as_float(((unsigned)h) << 16); }

__device__ inline void async_cp16(const void* g, void* l){
  __builtin_amdgcn_global_load_lds((const __attribute__((address_space(1))) void*)g,
                                   (__attribute__((address_space(3))) void*)l, 16, 0, 0);
}

// ---------------- CSR build (by destination) ----------------
__global__ void fill_int(int* p, int n, int v){
  int i = blockIdx.x * blockDim.x + threadIdx.x;
  if(i < n) p[i] = v;
}
__global__ void hist_dst(const int* __restrict__ dst, int* __restrict__ deg){
  int e = blockIdx.x * blockDim.x + threadIdx.x;
  if(e < Ee) atomicAdd(&deg[dst[e]], 1);
}
__global__ __launch_bounds__(1024) void scan_deg(const int* __restrict__ deg,
                                                 int* __restrict__ rowptr,
                                                 int* __restrict__ cursor){
  __shared__ int part[1024];
  int t = threadIdx.x;
  const int CH = (Nn + 1023) / 1024;
  int base = t * CH;
  int s = 0;
  for(int j = 0; j < CH; j++){ int idx = base + j; if(idx < Nn) s += deg[idx]; }
  part[t] = s;
  __syncthreads();
  for(int off = 1; off < 1024; off <<= 1){
    int v = (t >= off) ? part[t - off] : 0;
    __syncthreads();
    part[t] += v;
    __syncthreads();
  }
  int acc = part[t] - s;
  for(int j = 0; j < CH; j++){
    int idx = base + j;
    if(idx < Nn){ rowptr[idx] = acc; cursor[idx] = acc; acc += deg[idx]; }
  }
  if(t == 1023) rowptr[Nn] = part[1023];
}
// store SOURCE NODE ID directly (kills eid->src indirection in gat kernels)
__global__ void scatter_edges(const int* __restrict__ src, const int* __restrict__ dst,
                              int* __restrict__ cursor, int* __restrict__ srcv){
  int e = blockIdx.x * blockDim.x + threadIdx.x;
  if(e >= ETOT) return;
  int d, s;
  if(e < Ee){ d = dst[e]; s = src[e]; } else { d = e - Ee; s = d; }
  int pos = atomicAdd(&cursor[d], 1);
  srcv[pos] = s;
}

// ------------- W^T split: [2*Ca][K] bf16 hi/lo from Wl|Wr [K][Ca] -------------
__global__ __launch_bounds__(256) void wsplit(const float* __restrict__ Wl,
                                              const float* __restrict__ Wr,
                                              int K, int Ca,
                                              unsigned short* __restrict__ WTH,
                                              unsigned short* __restrict__ WTL){
  __shared__ float t[32][33];
  int k0 = blockIdx.x * 32, n0 = blockIdx.y * 32;
  int tx = threadIdx.x & 31, ty = threadIdx.x >> 5;
  #pragma unroll
  for(int j = 0; j < 4; j++){
    int kk = ty + j * 8;
    int n = n0 + tx;
    t[kk][tx] = (n < Ca) ? Wl[(size_t)(k0 + kk) * Ca + n]
                         : Wr[(size_t)(k0 + kk) * Ca + (n - Ca)];
  }
  __syncthreads();
  #pragma unroll
  for(int j = 0; j < 4; j++){
    int nn = ty + j * 8;
    float v = t[tx][nn];
    unsigned short hi = f2bf(v);
    unsigned short lo = f2bf(v - bf2f(hi));
    WTH[(size_t)(n0 + nn) * K + k0 + tx] = hi;
    WTL[(size_t)(n0 + nn) * K + k0 + tx] = lo;
  }
}

// ------- split-bf16 MFMA GEMM (2-term): Y = X @ WT^T + bias, tile 128x128 -------
// 512 threads = 8 waves (2 wm x 4 wn), wave tile 64x32, BK=32, double-buffered.
// LDS [g(kquad)][row][8] layout: all ds accesses are lane-consecutive 16B chunks.
__global__ __launch_bounds__(512) void gemm_2t(
    const float* __restrict__ X, int K, int niter,
    const unsigned short* __restrict__ WTH, const unsigned short* __restrict__ WTL,
    const float* __restrict__ bl, const float* __restrict__ br, int Ca,
    float* __restrict__ Ya, float* __restrict__ Yb)
{
  __shared__ unsigned short sA [2][128 * 32];   // 8 KB each buf
  __shared__ unsigned short sBh[2][128 * 32];
  __shared__ unsigned short sBl[2][128 * 32];

  const int tid  = threadIdx.x;
  const int lane = tid & 63;
  const int w    = tid >> 6;           // 0..7
  const int wm   = w & 1, wn = w >> 1; // 2 x 4
  const int bm   = blockIdx.y * 128;
  const int bn   = blockIdx.x * 128;

  f4v acc[4][2] = {};

  // A staging: thread -> (row = tid&127, kquad = tid>>7), 8 fp32 -> 1 b128 write
  const int arow  = tid & 127;
  const int aq    = tid >> 7;          // 0..3
  int gm0 = bm + arow; if(gm0 >= Nn) gm0 = Nn - 1;
  const float* aptr = X + (size_t)gm0 * K + aq * 8;
  const int awoff = (aq * 128 + arow) * 8;

  // B staging: chunk c = tid: g = tid>>7, n = tid&127; one cp16 per term
  const int bq = tid >> 7, bnr = tid & 127;
  const unsigned short* bhp = WTH + (size_t)(bn + bnr) * K + bq * 8;
  const unsigned short* blp = WTL + (size_t)(bn + bnr) * K + bq * 8;
  const int bldsoff = (w * 64) * 8;    // wave-uniform dest base

  // prologue -> buf 0
  async_cp16(bhp, &sBh[0][bldsoff]);
  async_cp16(blp, &sBl[0][bldsoff]);
  {
    float4 v0 = *(const float4*)(aptr);
    float4 v1 = *(const float4*)(aptr + 4);
    float fv[8] = {v0.x, v0.y, v0.z, v0.w, v1.x, v1.y, v1.z, v1.w};
    u16x8 hv;
    #pragma unroll
    for(int q = 0; q < 8; q++) hv[q] = f2bf(fv[q]);
    *(u16x8*)&sA[0][awoff] = hv;
  }

  const int mr = lane & 15;
  const int gq = lane >> 4;

  for(int it = 0; it < niter; it++){
    const int cur = it & 1, nxt = cur ^ 1;
    __syncthreads();                        // buf[cur] ready
    float4 v0, v1;
    const bool more = (it + 1 < niter);
    if(more){
      const int k0n = (it + 1) * 32;
      async_cp16(bhp + k0n, &sBh[nxt][bldsoff]);
      async_cp16(blp + k0n, &sBl[nxt][bldsoff]);
      v0 = *(const float4*)(aptr + k0n);
      v1 = *(const float4*)(aptr + k0n + 4);
    }
    s8v ah[4];
    #pragma unroll
    for(int i = 0; i < 4; i++)
      ah[i] = *(const s8v*)&sA[cur][(gq * 128 + wm * 64 + i * 16 + mr) * 8];
    #pragma unroll
    for(int j = 0; j < 2; j++){
      const int n = wn * 32 + j * 16 + mr;
      s8v bh  = *(const s8v*)&sBh[cur][(gq * 128 + n) * 8];
      s8v bl2 = *(const s8v*)&sBl[cur][(gq * 128 + n) * 8];
      #pragma unroll
      for(int i = 0; i < 4; i++){
        acc[i][j] = __builtin_amdgcn_mfma_f32_16x16x32_bf16(ah[i], bh,  acc[i][j], 0, 0, 0);
        acc[i][j] = __builtin_amdgcn_mfma_f32_16x16x32_bf16(ah[i], bl2, acc[i][j], 0, 0, 0);
      }
    }
    if(more){
      float fv[8] = {v0.x, v0.y, v0.z, v0.w, v1.x, v1.y, v1.z, v1.w};
      u16x8 hv;
      #pragma unroll
      for(int q = 0; q < 8; q++) hv[q] = f2bf(fv[q]);
      *(u16x8*)&sA[nxt][awoff] = hv;
    }
  }

  // epilogue: C/D map col=lane&15, row=(lane>>4)*4+reg
  const int quad = lane >> 4, col = lane & 15;
  #pragma unroll
  for(int j = 0; j < 2; j++){
    int gn = bn + wn * 32 + j * 16 + col;
    const float* bias = (gn < Ca) ? bl : br;
    float*       Y    = (gn < Ca) ? Ya : Yb;
    int cn = gn & (Ca - 1);               // Ca is power of two (256 / 64)
    float bv = bias[cn];
    #pragma unroll
    for(int i = 0; i < 4; i++){
      #pragma unroll
      for(int rg = 0; rg < 4; rg++){
        int gmm = bm + wm * 64 + i * 16 + quad * 4 + rg;
        if(gmm < Nn) Y[(size_t)gmm * Ca + cn] = acc[i][j][rg] + bv;
      }
    }
  }
}

// -------- fused GATv2 layer 1: wave/node, 4 online-softmax chains, srcv direct --------
__global__ __launch_bounds__(256) void gat_fused1(
    const int* __restrict__ rowptr, const int* __restrict__ srcv,
    const float* __restrict__ XL, const float* __restrict__ XR,
    const float* __restrict__ att, const float* __restrict__ bias,
    float* __restrict__ H)
{
  int node = blockIdx.x * 4 + (threadIdx.x >> 6);
  int lane = threadIdx.x & 63;
  if(node >= Nn) return;
  const float4 xr = *(const float4*)(XR + (size_t)node * 256 + lane * 4);
  const float4 a  = *(const float4*)(att + lane * 4);
  int r0 = rowptr[node], r1 = rowptr[node + 1];
  float m[4], l[4]; float4 acc[4];
  #pragma unroll
  for(int c = 0; c < 4; c++){ m[c] = -1e30f; l[c] = 0.f; acc[c] = make_float4(0,0,0,0); }
  for(int k = r0; k < r1; k += 4){
    int nv = r1 - k;
    int s[4]; float4 xl[4]; float p[4];
    #pragma unroll
    for(int c = 0; c < 4; c++){
      int kk = (c < nv) ? (k + c) : k;
      s[c] = srcv[kk];
    }
    #pragma unroll
    for(int c = 0; c < 4; c++) xl[c] = *(const float4*)(XL + (size_t)s[c] * 256 + lane * 4);
    #pragma unroll
    for(int c = 0; c < 4; c++){
      p[c] = lrelu(xl[c].x + xr.x) * a.x + lrelu(xl[c].y + xr.y) * a.y
           + lrelu(xl[c].z + xr.z) * a.z + lrelu(xl[c].w + xr.w) * a.w;
    }
    #pragma unroll
    for(int o = 8; o; o >>= 1){
      #pragma unroll
      for(int c = 0; c < 4; c++) p[c] += __shfl_xor(p[c], o, 64);
    }
    #pragma unroll
    for(int c = 0; c < 4; c++){
      if(c < nv){
        float mn = fmaxf(m[c], p[c]);
        float sc = __expf(m[c] - mn);
        float wg = __expf(p[c] - mn);
        l[c] = l[c] * sc + wg;
        acc[c].x = acc[c].x * sc + wg * xl[c].x;
        acc[c].y = acc[c].y * sc + wg * xl[c].y;
        acc[c].z = acc[c].z * sc + wg * xl[c].z;
        acc[c].w = acc[c].w * sc + wg * xl[c].w;
        m[c] = mn;
      }
    }
  }
  float M = fmaxf(fmaxf(m[0], m[1]), fmaxf(m[2], m[3]));
  float L = 0.f; float4 A4 = make_float4(0,0,0,0);
  #pragma unroll
  for(int c = 0; c < 4; c++){
    float sc = __expf(m[c] - M);
    L += l[c] * sc;
    A4.x += acc[c].x * sc; A4.y += acc[c].y * sc;
    A4.z += acc[c].z * sc; A4.w += acc[c].w * sc;
  }
  float inv = 1.f / (L + 1e-16f);
  const float4 b = *(const float4*)(bias + lane * 4);
  float4 o;
  o.x = fmaxf(A4.x * inv + b.x, 0.f);
  o.y = fmaxf(A4.y * inv + b.y, 0.f);
  o.z = fmaxf(A4.z * inv + b.z, 0.f);
  o.w = fmaxf(A4.w * inv + b.w, 0.f);
  *(float4*)(H + (size_t)node * 256 + lane * 4) = o;
}

// -------- fused GATv2 layer 2: wave/node, heads=1, 64 ch, 4 chains --------
__global__ __launch_bounds__(256) void gat_fused2(
    const int* __restrict__ rowptr, const int* __restrict__ srcv,
    const float* __restrict__ XL, const float* __restrict__ XR,
    const float* __restrict__ att, const float* __restrict__ bias,
    float* __restrict__ H)
{
  int node = blockIdx.x * 4 + (threadIdx.x >> 6);
  int lane = threadIdx.x & 63;
  if(node >= Nn) return;
  const float xr = XR[(size_t)node * 64 + lane];
  const float a = att[lane];
  int r0 = rowptr[node], r1 = rowptr[node + 1];
  float m[4], l[4], acc[4];
  #pragma unroll
  for(int c = 0; c < 4; c++){ m[c] = -1e30f; l[c] = 0.f; acc[c] = 0.f; }
  for(int k = r0; k < r1; k += 4){
    int nv = r1 - k;
    int s[4]; float xl[4]; float p[4];
    #pragma unroll
    for(int c = 0; c < 4; c++){
      int kk = (c < nv) ? (k + c) : k;
      s[c] = srcv[kk];
    }
    #pragma unroll
    for(int c = 0; c < 4; c++) xl[c] = XL[(size_t)s[c] * 64 + lane];
    #pragma unroll
    for(int c = 0; c < 4; c++) p[c] = lrelu(xl[c] + xr) * a;
    #pragma unroll
    for(int o = 32; o; o >>= 1){
      #pragma unroll
      for(int c = 0; c < 4; c++) p[c] += __shfl_xor(p[c], o, 64);
    }
    #pragma unroll
    for(int c = 0; c < 4; c++){
      if(c < nv){
        float mn = fmaxf(m[c], p[c]);
        float sc = __expf(m[c] - mn);
        float wg = __expf(p[c] - mn);
        l[c] = l[c] * sc + wg;
        acc[c] = acc[c] * sc + wg * xl[c];
        m[c] = mn;
      }
    }
  }
  float M = fmaxf(fmaxf(m[0], m[1]), fmaxf(m[2], m[3]));
  float L = 0.f, A1 = 0.f;
  #pragma unroll
  for(int c = 0; c < 4; c++){
    float sc = __expf(m[c] - M);
    L += l[c] * sc; A1 += acc[c] * sc;
  }
  float inv = 1.f / (L + 1e-16f);
  H[(size_t)node * 64 + lane] = fmaxf(A1 * inv + bias[lane], 0.f);
}

// ---------------- pool (batch sorted -> segmented, no atomics) + MLP head ----------------
__global__ void gbounds(const int* __restrict__ batch, int* __restrict__ gs){
  int g = blockIdx.x * blockDim.x + threadIdx.x;
  if(g > Gg) return;
  int lo = 0, hi = Nn;
  while(lo < hi){ int mid = (lo + hi) >> 1; if(batch[mid] < g) lo = mid + 1; else hi = mid; }
  gs[g] = lo;
}
__global__ __launch_bounds__(64) void pool_seg(const float* __restrict__ H2,
                                               const int* __restrict__ gs,
                                               float* __restrict__ GP){
  int g = blockIdx.x, t = threadIdx.x;
  int i0 = gs[g], i1 = gs[g + 1];
  float a0 = 0.f, a1 = 0.f, a2 = 0.f, a3 = 0.f;
  int i = i0;
  for(; i + 3 < i1; i += 4){
    a0 += H2[(size_t)i * 64 + t];       a1 += H2[(size_t)(i + 1) * 64 + t];
    a2 += H2[(size_t)(i + 2) * 64 + t]; a3 += H2[(size_t)(i + 3) * 64 + t];
  }
  for(; i < i1; i++) a0 += H2[(size_t)i * 64 + t];
  GP[(size_t)g * 64 + t] = (a0 + a1) + (a2 + a3);
}
__global__ __launch_bounds__(64) void mlp_head(const float* __restrict__ GP,
                                               const float* __restrict__ W3,
                                               const float* __restrict__ b3,
                                               const float* __restrict__ W4,
                                               const float* __restrict__ b4,
                                               float* __restrict__ out){
  int g = blockIdx.x;
  int j = threadIdx.x;
  __shared__ float sh[64];
  sh[j] = GP[(size_t)g * 64 + j];
  __syncthreads();
  float t = b3[j];
  #pragma unroll
  for(int k = 0; k < 64; k++) t = fmaf(sh[k], W3[k * 64 + j], t);
  t = fmaxf(t, 0.f);
  float p = t * W4[j];
  p = wave_sum(p);
  if(j == 0) out[g] = p + b4[0];
}

extern "C" void kernel_launch(void* const* d_in, const int* in_sizes, int n_in,
                              void* d_out, int out_size, void* d_ws, size_t ws_size,
                              hipStream_t stream)
{
  const float* x     = (const float*)d_in[0];
  const int*   ei    = (const int*)d_in[1];
  const int*   batch = (const int*)d_in[2];
  const float* Wl1   = (const float*)d_in[3];
  const float* bl1   = (const float*)d_in[4];
  const float* Wr1   = (const float*)d_in[5];
  const float* br1   = (const float*)d_in[6];
  const float* att1  = (const float*)d_in[7];
  const float* bias1 = (const float*)d_in[8];
  const float* Wl2   = (const float*)d_in[9];
  const float* bl2   = (const float*)d_in[10];
  const float* Wr2   = (const float*)d_in[11];
  const float* br2   = (const float*)d_in[12];
  const float* att2  = (const float*)d_in[13];
  const float* bias2 = (const float*)d_in[14];
  const float* W3    = (const float*)d_in[15];
  const float* b3    = (const float*)d_in[16];
  const float* W4    = (const float*)d_in[17];
  const float* b4    = (const float*)d_in[18];
  float* out = (float*)d_out;

  char* ws = (char*)d_ws;
  size_t off = 0;
  auto alloc = [&](size_t bytes) -> void* {
    void* p = ws + off;
    off += (bytes + 255) & ~(size_t)255;
    return p;
  };
  float* XL1  = (float*)alloc((size_t)Nn * 256 * 4);   // reused as XL2
  float* XR1  = (float*)alloc((size_t)Nn * 256 * 4);   // reused as XR2
  float* H1   = (float*)alloc((size_t)Nn * 256 * 4);
  unsigned short* WTH  = (unsigned short*)alloc((size_t)512 * Dd * 2);
  unsigned short* WTL  = (unsigned short*)alloc((size_t)512 * Dd * 2);
  unsigned short* WT2H = (unsigned short*)alloc((size_t)128 * 256 * 2);
  unsigned short* WT2L = (unsigned short*)alloc((size_t)128 * 256 * 2);
  int*   rowptr = (int*)alloc((size_t)(Nn + 1) * 4);
  int*   deg    = (int*)alloc((size_t)Nn * 4);
  int*   cursor = (int*)alloc((size_t)Nn * 4);
  int*   srcv   = (int*)alloc((size_t)ETOT * 4);
  float* H2   = (float*)alloc((size_t)Nn * 64 * 4);
  float* GP   = (float*)alloc((size_t)Gg * 64 * 4);
  int*   gs   = (int*)alloc((size_t)(Gg + 1) * 4);
  float* XL2 = XL1;
  float* XR2 = XR1;

  const int* srcA = ei;
  const int* dstA = ei + Ee;

  // CSR by destination (self-loop folded in via deg init = 1)
  fill_int<<<(Nn + 255) / 256, 256, 0, stream>>>(deg, Nn, 1);
  hist_dst<<<(Ee + 255) / 256, 256, 0, stream>>>(dstA, deg);
  scan_deg<<<1, 1024, 0, stream>>>(deg, rowptr, cursor);
  scatter_edges<<<(ETOT + 255) / 256, 256, 0, stream>>>(srcA, dstA, cursor, srcv);
  gbounds<<<1, 512, 0, stream>>>(batch, gs);

  // weight transposes + bf16 hi/lo splits
  wsplit<<<dim3(Dd / 32, 512 / 32), 256, 0, stream>>>(Wl1, Wr1, Dd, 256, WTH, WTL);
  wsplit<<<dim3(256 / 32, 128 / 32), 256, 0, stream>>>(Wl2, Wr2, 256, 64, WT2H, WT2L);

  // layer 1: X[20000x1280] @ WT^T -> XL1|XR1 [20000x256 each]
  gemm_2t<<<dim3(4, (Nn + 127) / 128), 512, 0, stream>>>(
      x, Dd, Dd / 32, WTH, WTL, bl1, br1, 256, XL1, XR1);
  gat_fused1<<<(Nn + 3) / 4, 256, 0, stream>>>(rowptr, srcv, XL1, XR1, att1, bias1, H1);

  // layer 2: H1[20000x256] @ WT2^T -> XL2|XR2 [20000x64 each]
  gemm_2t<<<dim3(1, (Nn + 127) / 128), 512, 0, stream>>>(
      H1, 256, 256 / 32, WT2H, WT2L, bl2, br2, 64, XL2, XR2);
  gat_fused2<<<(Nn + 3) / 4, 256, 0, stream>>>(rowptr, srcv, XL2, XR2, att2, bias2, H2);

  // pool + head
  pool_seg<<<Gg, 64, 0, stream>>>(H2, gs, GP);
  mlp_head<<<Gg, 64, 0, stream>>>(GP, W3, b3, W4, b4, out);
}

// Round 5
// 473.815 us; speedup vs baseline: 1.3565x; 1.1596x over previous
//
#include <hip/hip_runtime.h>

constexpr int Nn    = 20000;
constexpr int Ee    = 320000;
constexpr int Dd    = 1280;
constexpr int Gg    = 256;
constexpr int ETOT  = Ee + Nn;
#define NEG 0.2f

typedef __attribute__((ext_vector_type(8))) short s8v;            // 8 bf16 = 4 VGPR
typedef __attribute__((ext_vector_type(8))) unsigned short u16x8;
typedef __attribute__((ext_vector_type(4))) float f4v;            // MFMA acc

__device__ inline float lrelu(float v){ return v > 0.f ? v : NEG * v; }
__device__ inline float wave_sum(float v){
  #pragma unroll
  for(int o = 32; o; o >>= 1) v += __shfl_xor(v, o, 64);
  return v;
}
__device__ inline unsigned short f2bf(float x){
  unsigned u = __float_as_uint(x);
  return (unsigned short)((u + 0x7FFFu + ((u >> 16) & 1u)) >> 16);   // RNE
}
__device__ inline float bf2f(unsigned short h){ return __uint_as_float(((unsigned)h) << 16); }

__device__ inline void async_cp16(const void* g, void* l){
  __builtin_amdgcn_global_load_lds((const __attribute__((address_space(1))) void*)g,
                                   (__attribute__((address_space(3))) void*)l, 16, 0, 0);
}

// packed-weight offset: consumption order PB[tile][iter][wave][lane*8 ushorts]
// n = output row (0..nrows-1), k = reduction index; NITp = K/32
__device__ inline size_t pkoff(int n, int k, int NITp){
  return ((((size_t)(n >> 7) * NITp + (k >> 5)) * 8 + ((n >> 4) & 7)) * 512)
       + (((n & 15) * 4 + ((k >> 3) & 3)) * 8) + (k & 7);
}

// ---------------- CSR build (by destination) ----------------
__global__ void fill_int(int* p, int n, int v){
  int i = blockIdx.x * blockDim.x + threadIdx.x;
  if(i < n) p[i] = v;
}
__global__ void hist_dst(const int* __restrict__ dst, int* __restrict__ deg){
  int e = blockIdx.x * blockDim.x + threadIdx.x;
  if(e < Ee) atomicAdd(&deg[dst[e]], 1);
}
__global__ __launch_bounds__(1024) void scan_deg(const int* __restrict__ deg,
                                                 int* __restrict__ rowptr,
                                                 int* __restrict__ cursor){
  __shared__ int part[1024];
  int t = threadIdx.x;
  const int CH = (Nn + 1023) / 1024;
  int base = t * CH;
  int s = 0;
  for(int j = 0; j < CH; j++){ int idx = base + j; if(idx < Nn) s += deg[idx]; }
  part[t] = s;
  __syncthreads();
  for(int off = 1; off < 1024; off <<= 1){
    int v = (t >= off) ? part[t - off] : 0;
    __syncthreads();
    part[t] += v;
    __syncthreads();
  }
  int acc = part[t] - s;
  for(int j = 0; j < CH; j++){
    int idx = base + j;
    if(idx < Nn){ rowptr[idx] = acc; cursor[idx] = acc; acc += deg[idx]; }
  }
  if(t == 1023) rowptr[Nn] = part[1023];
}
__global__ void scatter_edges(const int* __restrict__ src, const int* __restrict__ dst,
                              int* __restrict__ cursor, int* __restrict__ srcv){
  int e = blockIdx.x * blockDim.x + threadIdx.x;
  if(e >= ETOT) return;
  int d, s;
  if(e < Ee){ d = dst[e]; s = src[e]; } else { d = e - Ee; s = d; }
  int pos = atomicAdd(&cursor[d], 1);
  srcv[pos] = s;
}

// ------------- W split to packed layout: from Wl|Wr [K][Ca] -------------
__global__ __launch_bounds__(256) void wsplit(const float* __restrict__ Wl,
                                              const float* __restrict__ Wr,
                                              int K, int Ca, int NITp,
                                              unsigned short* __restrict__ PBH,
                                              unsigned short* __restrict__ PBL){
  __shared__ float t[32][33];
  int k0 = blockIdx.x * 32, n0 = blockIdx.y * 32;
  int tx = threadIdx.x & 31, ty = threadIdx.x >> 5;
  #pragma unroll
  for(int j = 0; j < 4; j++){
    int kk = ty + j * 8;
    int n = n0 + tx;
    t[kk][tx] = (n < Ca) ? Wl[(size_t)(k0 + kk) * Ca + n]
                         : Wr[(size_t)(k0 + kk) * Ca + (n - Ca)];
  }
  __syncthreads();
  #pragma unroll
  for(int j = 0; j < 4; j++){
    int nn = ty + j * 8;
    float v = t[tx][nn];
    unsigned short hi = f2bf(v);
    unsigned short lo = f2bf(v - bf2f(hi));
    size_t o = pkoff(n0 + nn, k0 + tx, NITp);
    PBH[o] = hi;
    PBL[o] = lo;
  }
}

// ------- split-bf16 MFMA GEMM (2-term): Y = X @ W^T + bias, tile 128x128 -------
// 512 threads = 8 waves (2 wm x 4 wn), wave tile 64x32, BK=32, double-buffered.
// Staging fully lane-contiguous: B packed 1KB/wave cp16, A 32B/lane float4 pairs.
// LDS layout [row][kquad*16B]: bank-uniform for b128 writes and fragment reads.
__global__ __launch_bounds__(512) void gemm_2t(
    const float* __restrict__ X, int K, int niter,
    const unsigned short* __restrict__ PBH, const unsigned short* __restrict__ PBL,
    const float* __restrict__ bl, const float* __restrict__ br, int Ca,
    float* __restrict__ Ya, float* __restrict__ Yb)
{
  __shared__ unsigned short sA [2][128 * 32];   // 8 KB per buf
  __shared__ unsigned short sBh[2][128 * 32];
  __shared__ unsigned short sBl[2][128 * 32];

  const int tid  = threadIdx.x;
  const int lane = tid & 63;
  const int w    = tid >> 6;           // 0..7
  const int wm   = w & 1, wn = w >> 1; // 2 x 4
  const int bm   = blockIdx.y * 128;
  const int bn   = blockIdx.x * 128;

  f4v acc[4][2] = {};

  // A: row = w*16 + (lane>>2), kseg = lane&3 -> 4 lanes read 128B contiguous
  const int ar = w * 16 + (lane >> 2);
  int gmr = bm + ar; if(gmr >= Nn) gmr = Nn - 1;
  const float* aptr = X + (size_t)gmr * K + (lane & 3) * 8;
  const int awoff = ar * 32 + (lane & 3) * 8;          // ushorts

  // B: packed, wave reads 1KB contiguous; per-iter stride 4096 ushorts
  const size_t bbase = (((size_t)blockIdx.x * niter) * 8 + w) * 512 + lane * 8;
  const unsigned short* bhp = PBH + bbase;
  const unsigned short* blp = PBL + bbase;
  const int bldsoff = w * 512;                          // + lane*16B implicit

  // prologue -> buf 0
  async_cp16(bhp, &sBh[0][bldsoff]);
  async_cp16(blp, &sBl[0][bldsoff]);
  {
    float4 v0 = *(const float4*)(aptr);
    float4 v1 = *(const float4*)(aptr + 4);
    float fv[8] = {v0.x, v0.y, v0.z, v0.w, v1.x, v1.y, v1.z, v1.w};
    u16x8 hv;
    #pragma unroll
    for(int q = 0; q < 8; q++) hv[q] = f2bf(fv[q]);
    *(u16x8*)&sA[0][awoff] = hv;
  }

  const int mr = lane & 15;
  const int gq = lane >> 4;

  for(int it = 0; it < niter; it++){
    const int cur = it & 1, nxt = cur ^ 1;
    __syncthreads();                        // buf[cur] ready
    float4 v0, v1;
    const bool more = (it + 1 < niter);
    if(more){
      async_cp16(bhp + (size_t)(it + 1) * 4096, &sBh[nxt][bldsoff]);
      async_cp16(blp + (size_t)(it + 1) * 4096, &sBl[nxt][bldsoff]);
      v0 = *(const float4*)(aptr + (it + 1) * 32);
      v1 = *(const float4*)(aptr + (it + 1) * 32 + 4);
    }
    s8v ah[4];
    #pragma unroll
    for(int i = 0; i < 4; i++)
      ah[i] = *(const s8v*)&sA[cur][(wm * 64 + i * 16 + mr) * 32 + gq * 8];
    #pragma unroll
    for(int j = 0; j < 2; j++){
      const int n = wn * 32 + j * 16 + mr;
      s8v bh  = *(const s8v*)&sBh[cur][n * 32 + gq * 8];
      s8v bl2 = *(const s8v*)&sBl[cur][n * 32 + gq * 8];
      #pragma unroll
      for(int i = 0; i < 4; i++){
        acc[i][j] = __builtin_amdgcn_mfma_f32_16x16x32_bf16(ah[i], bh,  acc[i][j], 0, 0, 0);
        acc[i][j] = __builtin_amdgcn_mfma_f32_16x16x32_bf16(ah[i], bl2, acc[i][j], 0, 0, 0);
      }
    }
    if(more){
      float fv[8] = {v0.x, v0.y, v0.z, v0.w, v1.x, v1.y, v1.z, v1.w};
      u16x8 hv;
      #pragma unroll
      for(int q = 0; q < 8; q++) hv[q] = f2bf(fv[q]);
      *(u16x8*)&sA[nxt][awoff] = hv;
    }
  }

  // epilogue: C/D map col=lane&15, row=(lane>>4)*4+reg
  const int quad = lane >> 4, col = lane & 15;
  #pragma unroll
  for(int j = 0; j < 2; j++){
    int gn = bn + wn * 32 + j * 16 + col;
    const float* bias = (gn < Ca) ? bl : br;
    float*       Y    = (gn < Ca) ? Ya : Yb;
    int cn = gn & (Ca - 1);               // Ca is power of two (256 / 64)
    float bv = bias[cn];
    #pragma unroll
    for(int i = 0; i < 4; i++){
      #pragma unroll
      for(int rg = 0; rg < 4; rg++){
        int gmm = bm + wm * 64 + i * 16 + quad * 4 + rg;
        if(gmm < Nn) Y[(size_t)gmm * Ca + cn] = acc[i][j][rg] + bv;
      }
    }
  }
}

// -------- fused GATv2 layer 1: wave/node, 4 online-softmax chains --------
__global__ __launch_bounds__(256) void gat_fused1(
    const int* __restrict__ rowptr, const int* __restrict__ srcv,
    const float* __restrict__ XL, const float* __restrict__ XR,
    const float* __restrict__ att, const float* __restrict__ bias,
    float* __restrict__ H)
{
  int node = blockIdx.x * 4 + (threadIdx.x >> 6);
  int lane = threadIdx.x & 63;
  if(node >= Nn) return;
  const float4 xr = *(const float4*)(XR + (size_t)node * 256 + lane * 4);
  const float4 a  = *(const float4*)(att + lane * 4);
  int r0 = rowptr[node], r1 = rowptr[node + 1];
  float m[4], l[4]; float4 acc[4];
  #pragma unroll
  for(int c = 0; c < 4; c++){ m[c] = -1e30f; l[c] = 0.f; acc[c] = make_float4(0,0,0,0); }
  for(int k = r0; k < r1; k += 4){
    int nv = r1 - k;
    int s[4]; float4 xl[4]; float p[4];
    #pragma unroll
    for(int c = 0; c < 4; c++){
      int kk = (c < nv) ? (k + c) : k;
      s[c] = srcv[kk];
    }
    #pragma unroll
    for(int c = 0; c < 4; c++) xl[c] = *(const float4*)(XL + (size_t)s[c] * 256 + lane * 4);
    #pragma unroll
    for(int c = 0; c < 4; c++){
      p[c] = lrelu(xl[c].x + xr.x) * a.x + lrelu(xl[c].y + xr.y) * a.y
           + lrelu(xl[c].z + xr.z) * a.z + lrelu(xl[c].w + xr.w) * a.w;
    }
    #pragma unroll
    for(int o = 8; o; o >>= 1){
      #pragma unroll
      for(int c = 0; c < 4; c++) p[c] += __shfl_xor(p[c], o, 64);
    }
    #pragma unroll
    for(int c = 0; c < 4; c++){
      if(c < nv){
        float mn = fmaxf(m[c], p[c]);
        float sc = __expf(m[c] - mn);
        float wg = __expf(p[c] - mn);
        l[c] = l[c] * sc + wg;
        acc[c].x = acc[c].x * sc + wg * xl[c].x;
        acc[c].y = acc[c].y * sc + wg * xl[c].y;
        acc[c].z = acc[c].z * sc + wg * xl[c].z;
        acc[c].w = acc[c].w * sc + wg * xl[c].w;
        m[c] = mn;
      }
    }
  }
  float M = fmaxf(fmaxf(m[0], m[1]), fmaxf(m[2], m[3]));
  float L = 0.f; float4 A4 = make_float4(0,0,0,0);
  #pragma unroll
  for(int c = 0; c < 4; c++){
    float sc = __expf(m[c] - M);
    L += l[c] * sc;
    A4.x += acc[c].x * sc; A4.y += acc[c].y * sc;
    A4.z += acc[c].z * sc; A4.w += acc[c].w * sc;
  }
  float inv = 1.f / (L + 1e-16f);
  const float4 b = *(const float4*)(bias + lane * 4);
  float4 o;
  o.x = fmaxf(A4.x * inv + b.x, 0.f);
  o.y = fmaxf(A4.y * inv + b.y, 0.f);
  o.z = fmaxf(A4.z * inv + b.z, 0.f);
  o.w = fmaxf(A4.w * inv + b.w, 0.f);
  *(float4*)(H + (size_t)node * 256 + lane * 4) = o;
}

// -------- fused GATv2 layer 2: wave/node, heads=1, 64 ch, 4 chains --------
__global__ __launch_bounds__(256) void gat_fused2(
    const int* __restrict__ rowptr, const int* __restrict__ srcv,
    const float* __restrict__ XL, const float* __restrict__ XR,
    const float* __restrict__ att, const float* __restrict__ bias,
    float* __restrict__ H)
{
  int node = blockIdx.x * 4 + (threadIdx.x >> 6);
  int lane = threadIdx.x & 63;
  if(node >= Nn) return;
  const float xr = XR[(size_t)node * 64 + lane];
  const float a = att[lane];
  int r0 = rowptr[node], r1 = rowptr[node + 1];
  float m[4], l[4], acc[4];
  #pragma unroll
  for(int c = 0; c < 4; c++){ m[c] = -1e30f; l[c] = 0.f; acc[c] = 0.f; }
  for(int k = r0; k < r1; k += 4){
    int nv = r1 - k;
    int s[4]; float xl[4]; float p[4];
    #pragma unroll
    for(int c = 0; c < 4; c++){
      int kk = (c < nv) ? (k + c) : k;
      s[c] = srcv[kk];
    }
    #pragma unroll
    for(int c = 0; c < 4; c++) xl[c] = XL[(size_t)s[c] * 64 + lane];
    #pragma unroll
    for(int c = 0; c < 4; c++) p[c] = lrelu(xl[c] + xr) * a;
    #pragma unroll
    for(int o = 32; o; o >>= 1){
      #pragma unroll
      for(int c = 0; c < 4; c++) p[c] += __shfl_xor(p[c], o, 64);
    }
    #pragma unroll
    for(int c = 0; c < 4; c++){
      if(c < nv){
        float mn = fmaxf(m[c], p[c]);
        float sc = __expf(m[c] - mn);
        float wg = __expf(p[c] - mn);
        l[c] = l[c] * sc + wg;
        acc[c] = acc[c] * sc + wg * xl[c];
        m[c] = mn;
      }
    }
  }
  float M = fmaxf(fmaxf(m[0], m[1]), fmaxf(m[2], m[3]));
  float L = 0.f, A1 = 0.f;
  #pragma unroll
  for(int c = 0; c < 4; c++){
    float sc = __expf(m[c] - M);
    L += l[c] * sc; A1 += acc[c] * sc;
  }
  float inv = 1.f / (L + 1e-16f);
  H[(size_t)node * 64 + lane] = fmaxf(A1 * inv + bias[lane], 0.f);
}

// ---------------- pool (segmented, no atomics) + MLP head ----------------
__global__ void gbounds(const int* __restrict__ batch, int* __restrict__ gs){
  int g = blockIdx.x * blockDim.x + threadIdx.x;
  if(g > Gg) return;
  int lo = 0, hi = Nn;
  while(lo < hi){ int mid = (lo + hi) >> 1; if(batch[mid] < g) lo = mid + 1; else hi = mid; }
  gs[g] = lo;
}
__global__ __launch_bounds__(64) void pool_seg(const float* __restrict__ H2,
                                               const int* __restrict__ gs,
                                               float* __restrict__ GP){
  int g = blockIdx.x, t = threadIdx.x;
  int i0 = gs[g], i1 = gs[g + 1];
  float a0 = 0.f, a1 = 0.f, a2 = 0.f, a3 = 0.f;
  int i = i0;
  for(; i + 3 < i1; i += 4){
    a0 += H2[(size_t)i * 64 + t];       a1 += H2[(size_t)(i + 1) * 64 + t];
    a2 += H2[(size_t)(i + 2) * 64 + t]; a3 += H2[(size_t)(i + 3) * 64 + t];
  }
  for(; i < i1; i++) a0 += H2[(size_t)i * 64 + t];
  GP[(size_t)g * 64 + t] = (a0 + a1) + (a2 + a3);
}
__global__ __launch_bounds__(64) void mlp_head(const float* __restrict__ GP,
                                               const float* __restrict__ W3,
                                               const float* __restrict__ b3,
                                               const float* __restrict__ W4,
                                               const float* __restrict__ b4,
                                               float* __restrict__ out){
  int g = blockIdx.x;
  int j = threadIdx.x;
  __shared__ float sh[64];
  sh[j] = GP[(size_t)g * 64 + j];
  __syncthreads();
  float t = b3[j];
  #pragma unroll
  for(int k = 0; k < 64; k++) t = fmaf(sh[k], W3[k * 64 + j], t);
  t = fmaxf(t, 0.f);
  float p = t * W4[j];
  p = wave_sum(p);
  if(j == 0) out[g] = p + b4[0];
}

extern "C" void kernel_launch(void* const* d_in, const int* in_sizes, int n_in,
                              void* d_out, int out_size, void* d_ws, size_t ws_size,
                              hipStream_t stream)
{
  const float* x     = (const float*)d_in[0];
  const int*   ei    = (const int*)d_in[1];
  const int*   batch = (const int*)d_in[2];
  const float* Wl1   = (const float*)d_in[3];
  const float* bl1   = (const float*)d_in[4];
  const float* Wr1   = (const float*)d_in[5];
  const float* br1   = (const float*)d_in[6];
  const float* att1  = (const float*)d_in[7];
  const float* bias1 = (const float*)d_in[8];
  const float* Wl2   = (const float*)d_in[9];
  const float* bl2   = (const float*)d_in[10];
  const float* Wr2   = (const float*)d_in[11];
  const float* br2   = (const float*)d_in[12];
  const float* att2  = (const float*)d_in[13];
  const float* bias2 = (const float*)d_in[14];
  const float* W3    = (const float*)d_in[15];
  const float* b3    = (const float*)d_in[16];
  const float* W4    = (const float*)d_in[17];
  const float* b4    = (const float*)d_in[18];
  float* out = (float*)d_out;

  char* ws = (char*)d_ws;
  size_t off = 0;
  auto alloc = [&](size_t bytes) -> void* {
    void* p = ws + off;
    off += (bytes + 255) & ~(size_t)255;
    return p;
  };
  float* XL1  = (float*)alloc((size_t)Nn * 256 * 4);   // reused as XL2
  float* XR1  = (float*)alloc((size_t)Nn * 256 * 4);   // reused as XR2
  float* H1   = (float*)alloc((size_t)Nn * 256 * 4);
  unsigned short* PB1H = (unsigned short*)alloc((size_t)512 * Dd * 2);
  unsigned short* PB1L = (unsigned short*)alloc((size_t)512 * Dd * 2);
  unsigned short* PB2H = (unsigned short*)alloc((size_t)128 * 256 * 2);
  unsigned short* PB2L = (unsigned short*)alloc((size_t)128 * 256 * 2);
  int*   rowptr = (int*)alloc((size_t)(Nn + 1) * 4);
  int*   deg    = (int*)alloc((size_t)Nn * 4);
  int*   cursor = (int*)alloc((size_t)Nn * 4);
  int*   srcv   = (int*)alloc((size_t)ETOT * 4);
  float* H2   = (float*)alloc((size_t)Nn * 64 * 4);
  float* GP   = (float*)alloc((size_t)Gg * 64 * 4);
  int*   gs   = (int*)alloc((size_t)(Gg + 1) * 4);
  float* XL2 = XL1;
  float* XR2 = XR1;

  const int* srcA = ei;
  const int* dstA = ei + Ee;

  // CSR by destination (self-loop folded in via deg init = 1)
  fill_int<<<(Nn + 255) / 256, 256, 0, stream>>>(deg, Nn, 1);
  hist_dst<<<(Ee + 255) / 256, 256, 0, stream>>>(dstA, deg);
  scan_deg<<<1, 1024, 0, stream>>>(deg, rowptr, cursor);
  scatter_edges<<<(ETOT + 255) / 256, 256, 0, stream>>>(srcA, dstA, cursor, srcv);
  gbounds<<<1, 512, 0, stream>>>(batch, gs);

  // weight transposes + bf16 hi/lo splits into packed consumption-order layout
  wsplit<<<dim3(Dd / 32, 512 / 32), 256, 0, stream>>>(Wl1, Wr1, Dd, 256, Dd / 32, PB1H, PB1L);
  wsplit<<<dim3(256 / 32, 128 / 32), 256, 0, stream>>>(Wl2, Wr2, 256, 64, 256 / 32, PB2H, PB2L);

  // layer 1: X[20000x1280] @ W^T -> XL1|XR1 [20000x256 each]
  gemm_2t<<<dim3(4, (Nn + 127) / 128), 512, 0, stream>>>(
      x, Dd, Dd / 32, PB1H, PB1L, bl1, br1, 256, XL1, XR1);
  gat_fused1<<<(Nn + 3) / 4, 256, 0, stream>>>(rowptr, srcv, XL1, XR1, att1, bias1, H1);

  // layer 2: H1[20000x256] @ W2^T -> XL2|XR2 [20000x64 each]
  gemm_2t<<<dim3(1, (Nn + 127) / 128), 512, 0, stream>>>(
      H1, 256, 256 / 32, PB2H, PB2L, bl2, br2, 64, XL2, XR2);
  gat_fused2<<<(Nn + 3) / 4, 256, 0, stream>>>(rowptr, srcv, XL2, XR2, att2, bias2, H2);

  // pool + head
  pool_seg<<<Gg, 64, 0, stream>>>(H2, gs, GP);
  mlp_head<<<Gg, 64, 0, stream>>>(GP, W3, b3, W4, b4, out);
}

// Round 6
// 466.066 us; speedup vs baseline: 1.3791x; 1.0166x over previous
//
#include <hip/hip_runtime.h>

constexpr int Nn    = 20000;
constexpr int Ee    = 320000;
constexpr int Dd    = 1280;
constexpr int Gg    = 256;
constexpr int ETOT  = Ee + Nn;
#define NEG 0.2f

typedef __attribute__((ext_vector_type(8))) short s8v;            // 8 bf16 = 4 VGPR
typedef __attribute__((ext_vector_type(8))) unsigned short u16x8;
typedef __attribute__((ext_vector_type(4))) float f4v;            // MFMA acc

__device__ inline float lrelu(float v){ return v > 0.f ? v : NEG * v; }
__device__ inline float wave_sum(float v){
  #pragma unroll
  for(int o = 32; o; o >>= 1) v += __shfl_xor(v, o, 64);
  return v;
}
__device__ inline unsigned short f2bf(float x){
  unsigned u = __float_as_uint(x);
  return (unsigned short)((u + 0x7FFFu + ((u >> 16) & 1u)) >> 16);   // RNE
}
__device__ inline float bf2f(unsigned short h){ return __uint_as_float(((unsigned)h) << 16); }

__device__ inline void async_cp16(const void* g, void* l){
  __builtin_amdgcn_global_load_lds((const __attribute__((address_space(1))) void*)g,
                                   (__attribute__((address_space(3))) void*)l, 16, 0, 0);
}

// packed-weight offset, consumption order: PB[tile][iter][chunk=gq*128+n][k&7]
// (chunk c staged by thread tid=c via one cp16; fragment reads phase-consecutive)
__device__ inline size_t pkoff(int n, int k, int NITp){
  return ((((size_t)(n >> 7) * NITp + (k >> 5)) * 512)
          + (((k >> 3) & 3) * 128 + (n & 127))) * 8 + (k & 7);
}

// ---------------- CSR build (by destination) ----------------
__global__ void fill_int(int* p, int n, int v){
  int i = blockIdx.x * blockDim.x + threadIdx.x;
  if(i < n) p[i] = v;
}
__global__ void hist_dst(const int* __restrict__ dst, int* __restrict__ deg){
  int e = blockIdx.x * blockDim.x + threadIdx.x;
  if(e < Ee) atomicAdd(&deg[dst[e]], 1);
}
__global__ __launch_bounds__(1024) void scan_deg(const int* __restrict__ deg,
                                                 int* __restrict__ rowptr,
                                                 int* __restrict__ cursor){
  __shared__ int part[1024];
  int t = threadIdx.x;
  const int CH = (Nn + 1023) / 1024;
  int base = t * CH;
  int s = 0;
  for(int j = 0; j < CH; j++){ int idx = base + j; if(idx < Nn) s += deg[idx]; }
  part[t] = s;
  __syncthreads();
  for(int off = 1; off < 1024; off <<= 1){
    int v = (t >= off) ? part[t - off] : 0;
    __syncthreads();
    part[t] += v;
    __syncthreads();
  }
  int acc = part[t] - s;
  for(int j = 0; j < CH; j++){
    int idx = base + j;
    if(idx < Nn){ rowptr[idx] = acc; cursor[idx] = acc; acc += deg[idx]; }
  }
  if(t == 1023) rowptr[Nn] = part[1023];
}
__global__ void scatter_edges(const int* __restrict__ src, const int* __restrict__ dst,
                              int* __restrict__ cursor, int* __restrict__ srcv){
  int e = blockIdx.x * blockDim.x + threadIdx.x;
  if(e >= ETOT) return;
  int d, s;
  if(e < Ee){ d = dst[e]; s = src[e]; } else { d = e - Ee; s = d; }
  int pos = atomicAdd(&cursor[d], 1);
  srcv[pos] = s;
}

// ------------- W split to packed layout: from Wl|Wr [K][Ca] -------------
__global__ __launch_bounds__(256) void wsplit(const float* __restrict__ Wl,
                                              const float* __restrict__ Wr,
                                              int K, int Ca, int NITp,
                                              unsigned short* __restrict__ PBH,
                                              unsigned short* __restrict__ PBL){
  __shared__ float t[32][33];
  int k0 = blockIdx.x * 32, n0 = blockIdx.y * 32;
  int tx = threadIdx.x & 31, ty = threadIdx.x >> 5;
  #pragma unroll
  for(int j = 0; j < 4; j++){
    int kk = ty + j * 8;
    int n = n0 + tx;
    t[kk][tx] = (n < Ca) ? Wl[(size_t)(k0 + kk) * Ca + n]
                         : Wr[(size_t)(k0 + kk) * Ca + (n - Ca)];
  }
  __syncthreads();
  #pragma unroll
  for(int j = 0; j < 4; j++){
    int nn = ty + j * 8;
    float v = t[tx][nn];
    unsigned short hi = f2bf(v);
    unsigned short lo = f2bf(v - bf2f(hi));
    size_t o = pkoff(n0 + nn, k0 + tx, NITp);
    PBH[o] = hi;
    PBL[o] = lo;
  }
}

// ------- split-bf16 MFMA GEMM (2-term): Y = X @ W^T + bias, tile 128x128 -------
// 512 threads = 8 waves (2 wm x 4 wn), wave tile 64x32, BK=32, double-buffered.
// B: packed consumption-order, 1KB/wave contiguous cp16 -> zero-conflict chunk LDS.
// A: coalesced float4 pairs, gq-rotated chunk LDS (2-way write, 0-conflict reads).
// 1-D grid with XCD swizzle: the ntx n-tiles sharing X rows land on one XCD.
__global__ __launch_bounds__(512) void gemm_2t(
    const float* __restrict__ X, int K, int niter, int ntx, int nty,
    const unsigned short* __restrict__ PBH, const unsigned short* __restrict__ PBL,
    const float* __restrict__ bl, const float* __restrict__ br, int Ca,
    float* __restrict__ Ya, float* __restrict__ Yb)
{
  int xb, yb;
  if(ntx == 4){
    int id = blockIdx.x;
    int g = id >> 5, rem = id & 31;
    xb = rem >> 3; yb = g * 8 + (rem & 7);
  } else { xb = 0; yb = blockIdx.x; }
  if(yb >= nty) return;

  __shared__ unsigned short sA [2][4096];   // 512 chunks x 16B = 8 KB per buf
  __shared__ unsigned short sBh[2][4096];
  __shared__ unsigned short sBl[2][4096];

  const int tid  = threadIdx.x;
  const int lane = tid & 63;
  const int w    = tid >> 6;           // 0..7
  const int wm   = w & 1, wn = w >> 1; // 2 x 4
  const int bm   = yb * 128;
  const int bn   = xb * 128;

  f4v acc[4][2] = {};

  // A staging: row = w*16 + (lane>>2), kq = lane&3 -> 4 lanes cover 128B/row
  const int ar = w * 16 + (lane >> 2);
  const int aq = lane & 3;
  int gmr = bm + ar; if(gmr >= Nn) gmr = Nn - 1;
  const float* aptr = X + (size_t)gmr * K + aq * 8;
  const int awoff = (aq * 128 + ((ar + aq * 4) & 127)) * 8;   // rotated chunk

  // B staging: chunk = tid, 1KB/wave contiguous; per-iter stride 4096 ushorts
  const size_t bbase = ((size_t)xb * niter) * 4096 + tid * 8;
  const unsigned short* bhp = PBH + bbase;
  const unsigned short* blp = PBL + bbase;
  const int bldsoff = w * 512;          // + lane*16B implicit

  // prologue -> buf 0
  async_cp16(bhp, &sBh[0][bldsoff]);
  async_cp16(blp, &sBl[0][bldsoff]);
  {
    float4 v0 = *(const float4*)(aptr);
    float4 v1 = *(const float4*)(aptr + 4);
    float fv[8] = {v0.x, v0.y, v0.z, v0.w, v1.x, v1.y, v1.z, v1.w};
    u16x8 hv;
    #pragma unroll
    for(int q = 0; q < 8; q++) hv[q] = f2bf(fv[q]);
    *(u16x8*)&sA[0][awoff] = hv;
  }

  const int mr = lane & 15;
  const int gq = lane >> 4;
  // iteration-invariant fragment offsets (ushorts)
  int aoff[4], boff[2];
  #pragma unroll
  for(int i = 0; i < 4; i++){
    int row = wm * 64 + i * 16 + mr;
    aoff[i] = (gq * 128 + ((row + gq * 4) & 127)) * 8;
  }
  #pragma unroll
  for(int j = 0; j < 2; j++){
    int n = wn * 32 + j * 16 + mr;
    boff[j] = (gq * 128 + n) * 8;
  }

  for(int it = 0; it < niter; it++){
    const int cur = it & 1, nxt = cur ^ 1;
    __syncthreads();                        // buf[cur] ready
    float4 v0, v1;
    const bool more = (it + 1 < niter);
    if(more){
      async_cp16(bhp + (size_t)(it + 1) * 4096, &sBh[nxt][bldsoff]);
      async_cp16(blp + (size_t)(it + 1) * 4096, &sBl[nxt][bldsoff]);
      v0 = *(const float4*)(aptr + (it + 1) * 32);
      v1 = *(const float4*)(aptr + (it + 1) * 32 + 4);
    }
    s8v ah[4];
    #pragma unroll
    for(int i = 0; i < 4; i++) ah[i] = *(const s8v*)&sA[cur][aoff[i]];
    #pragma unroll
    for(int j = 0; j < 2; j++){
      s8v bh  = *(const s8v*)&sBh[cur][boff[j]];
      s8v bl2 = *(const s8v*)&sBl[cur][boff[j]];
      #pragma unroll
      for(int i = 0; i < 4; i++){
        acc[i][j] = __builtin_amdgcn_mfma_f32_16x16x32_bf16(ah[i], bh,  acc[i][j], 0, 0, 0);
        acc[i][j] = __builtin_amdgcn_mfma_f32_16x16x32_bf16(ah[i], bl2, acc[i][j], 0, 0, 0);
      }
    }
    if(more){
      float fv[8] = {v0.x, v0.y, v0.z, v0.w, v1.x, v1.y, v1.z, v1.w};
      u16x8 hv;
      #pragma unroll
      for(int q = 0; q < 8; q++) hv[q] = f2bf(fv[q]);
      *(u16x8*)&sA[nxt][awoff] = hv;
    }
  }

  // epilogue: C/D map col=lane&15, row=(lane>>4)*4+reg
  const int quad = lane >> 4, col = lane & 15;
  #pragma unroll
  for(int j = 0; j < 2; j++){
    int gn = bn + wn * 32 + j * 16 + col;
    const float* bias = (gn < Ca) ? bl : br;
    float*       Y    = (gn < Ca) ? Ya : Yb;
    int cn = gn & (Ca - 1);               // Ca is power of two (256 / 64)
    float bv = bias[cn];
    #pragma unroll
    for(int i = 0; i < 4; i++){
      #pragma unroll
      for(int rg = 0; rg < 4; rg++){
        int gmm = bm + wm * 64 + i * 16 + quad * 4 + rg;
        if(gmm < Nn) Y[(size_t)gmm * Ca + cn] = acc[i][j][rg] + bv;
      }
    }
  }
}

// -------- fused GATv2 layer 1: wave/node, 4 online-softmax chains --------
__global__ __launch_bounds__(256) void gat_fused1(
    const int* __restrict__ rowptr, const int* __restrict__ srcv,
    const float* __restrict__ XL, const float* __restrict__ XR,
    const float* __restrict__ att, const float* __restrict__ bias,
    float* __restrict__ H)
{
  int node = blockIdx.x * 4 + (threadIdx.x >> 6);
  int lane = threadIdx.x & 63;
  if(node >= Nn) return;
  const float4 xr = *(const float4*)(XR + (size_t)node * 256 + lane * 4);
  const float4 a  = *(const float4*)(att + lane * 4);
  int r0 = rowptr[node], r1 = rowptr[node + 1];
  float m[4], l[4]; float4 acc[4];
  #pragma unroll
  for(int c = 0; c < 4; c++){ m[c] = -1e30f; l[c] = 0.f; acc[c] = make_float4(0,0,0,0); }
  for(int k = r0; k < r1; k += 4){
    int nv = r1 - k;
    int s[4]; float4 xl[4]; float p[4];
    #pragma unroll
    for(int c = 0; c < 4; c++){
      int kk = (c < nv) ? (k + c) : k;
      s[c] = srcv[kk];
    }
    #pragma unroll
    for(int c = 0; c < 4; c++) xl[c] = *(const float4*)(XL + (size_t)s[c] * 256 + lane * 4);
    #pragma unroll
    for(int c = 0; c < 4; c++){
      p[c] = lrelu(xl[c].x + xr.x) * a.x + lrelu(xl[c].y + xr.y) * a.y
           + lrelu(xl[c].z + xr.z) * a.z + lrelu(xl[c].w + xr.w) * a.w;
    }
    #pragma unroll
    for(int o = 8; o; o >>= 1){
      #pragma unroll
      for(int c = 0; c < 4; c++) p[c] += __shfl_xor(p[c], o, 64);
    }
    #pragma unroll
    for(int c = 0; c < 4; c++){
      if(c < nv){
        float mn = fmaxf(m[c], p[c]);
        float sc = __expf(m[c] - mn);
        float wg = __expf(p[c] - mn);
        l[c] = l[c] * sc + wg;
        acc[c].x = acc[c].x * sc + wg * xl[c].x;
        acc[c].y = acc[c].y * sc + wg * xl[c].y;
        acc[c].z = acc[c].z * sc + wg * xl[c].z;
        acc[c].w = acc[c].w * sc + wg * xl[c].w;
        m[c] = mn;
      }
    }
  }
  float M = fmaxf(fmaxf(m[0], m[1]), fmaxf(m[2], m[3]));
  float L = 0.f; float4 A4 = make_float4(0,0,0,0);
  #pragma unroll
  for(int c = 0; c < 4; c++){
    float sc = __expf(m[c] - M);
    L += l[c] * sc;
    A4.x += acc[c].x * sc; A4.y += acc[c].y * sc;
    A4.z += acc[c].z * sc; A4.w += acc[c].w * sc;
  }
  float inv = 1.f / (L + 1e-16f);
  const float4 b = *(const float4*)(bias + lane * 4);
  float4 o;
  o.x = fmaxf(A4.x * inv + b.x, 0.f);
  o.y = fmaxf(A4.y * inv + b.y, 0.f);
  o.z = fmaxf(A4.z * inv + b.z, 0.f);
  o.w = fmaxf(A4.w * inv + b.w, 0.f);
  *(float4*)(H + (size_t)node * 256 + lane * 4) = o;
}

// -------- fused GATv2 layer 2: wave/node, heads=1, 64 ch, 4 chains --------
__global__ __launch_bounds__(256) void gat_fused2(
    const int* __restrict__ rowptr, const int* __restrict__ srcv,
    const float* __restrict__ XL, const float* __restrict__ XR,
    const float* __restrict__ att, const float* __restrict__ bias,
    float* __restrict__ H)
{
  int node = blockIdx.x * 4 + (threadIdx.x >> 6);
  int lane = threadIdx.x & 63;
  if(node >= Nn) return;
  const float xr = XR[(size_t)node * 64 + lane];
  const float a = att[lane];
  int r0 = rowptr[node], r1 = rowptr[node + 1];
  float m[4], l[4], acc[4];
  #pragma unroll
  for(int c = 0; c < 4; c++){ m[c] = -1e30f; l[c] = 0.f; acc[c] = 0.f; }
  for(int k = r0; k < r1; k += 4){
    int nv = r1 - k;
    int s[4]; float xl[4]; float p[4];
    #pragma unroll
    for(int c = 0; c < 4; c++){
      int kk = (c < nv) ? (k + c) : k;
      s[c] = srcv[kk];
    }
    #pragma unroll
    for(int c = 0; c < 4; c++) xl[c] = XL[(size_t)s[c] * 64 + lane];
    #pragma unroll
    for(int c = 0; c < 4; c++) p[c] = lrelu(xl[c] + xr) * a;
    #pragma unroll
    for(int o = 32; o; o >>= 1){
      #pragma unroll
      for(int c = 0; c < 4; c++) p[c] += __shfl_xor(p[c], o, 64);
    }
    #pragma unroll
    for(int c = 0; c < 4; c++){
      if(c < nv){
        float mn = fmaxf(m[c], p[c]);
        float sc = __expf(m[c] - mn);
        float wg = __expf(p[c] - mn);
        l[c] = l[c] * sc + wg;
        acc[c] = acc[c] * sc + wg * xl[c];
        m[c] = mn;
      }
    }
  }
  float M = fmaxf(fmaxf(m[0], m[1]), fmaxf(m[2], m[3]));
  float L = 0.f, A1 = 0.f;
  #pragma unroll
  for(int c = 0; c < 4; c++){
    float sc = __expf(m[c] - M);
    L += l[c] * sc; A1 += acc[c] * sc;
  }
  float inv = 1.f / (L + 1e-16f);
  H[(size_t)node * 64 + lane] = fmaxf(A1 * inv + bias[lane], 0.f);
}

// ---------------- pool (segmented, no atomics) + MLP head ----------------
__global__ void gbounds(const int* __restrict__ batch, int* __restrict__ gs){
  int g = blockIdx.x * blockDim.x + threadIdx.x;
  if(g > Gg) return;
  int lo = 0, hi = Nn;
  while(lo < hi){ int mid = (lo + hi) >> 1; if(batch[mid] < g) lo = mid + 1; else hi = mid; }
  gs[g] = lo;
}
__global__ __launch_bounds__(64) void pool_seg(const float* __restrict__ H2,
                                               const int* __restrict__ gs,
                                               float* __restrict__ GP){
  int g = blockIdx.x, t = threadIdx.x;
  int i0 = gs[g], i1 = gs[g + 1];
  float a0 = 0.f, a1 = 0.f, a2 = 0.f, a3 = 0.f;
  int i = i0;
  for(; i + 3 < i1; i += 4){
    a0 += H2[(size_t)i * 64 + t];       a1 += H2[(size_t)(i + 1) * 64 + t];
    a2 += H2[(size_t)(i + 2) * 64 + t]; a3 += H2[(size_t)(i + 3) * 64 + t];
  }
  for(; i < i1; i++) a0 += H2[(size_t)i * 64 + t];
  GP[(size_t)g * 64 + t] = (a0 + a1) + (a2 + a3);
}
__global__ __launch_bounds__(64) void mlp_head(const float* __restrict__ GP,
                                               const float* __restrict__ W3,
                                               const float* __restrict__ b3,
                                               const float* __restrict__ W4,
                                               const float* __restrict__ b4,
                                               float* __restrict__ out){
  int g = blockIdx.x;
  int j = threadIdx.x;
  __shared__ float sh[64];
  sh[j] = GP[(size_t)g * 64 + j];
  __syncthreads();
  float t = b3[j];
  #pragma unroll
  for(int k = 0; k < 64; k++) t = fmaf(sh[k], W3[k * 64 + j], t);
  t = fmaxf(t, 0.f);
  float p = t * W4[j];
  p = wave_sum(p);
  if(j == 0) out[g] = p + b4[0];
}

extern "C" void kernel_launch(void* const* d_in, const int* in_sizes, int n_in,
                              void* d_out, int out_size, void* d_ws, size_t ws_size,
                              hipStream_t stream)
{
  const float* x     = (const float*)d_in[0];
  const int*   ei    = (const int*)d_in[1];
  const int*   batch = (const int*)d_in[2];
  const float* Wl1   = (const float*)d_in[3];
  const float* bl1   = (const float*)d_in[4];
  const float* Wr1   = (const float*)d_in[5];
  const float* br1   = (const float*)d_in[6];
  const float* att1  = (const float*)d_in[7];
  const float* bias1 = (const float*)d_in[8];
  const float* Wl2   = (const float*)d_in[9];
  const float* bl2   = (const float*)d_in[10];
  const float* Wr2   = (const float*)d_in[11];
  const float* br2   = (const float*)d_in[12];
  const float* att2  = (const float*)d_in[13];
  const float* bias2 = (const float*)d_in[14];
  const float* W3    = (const float*)d_in[15];
  const float* b3    = (const float*)d_in[16];
  const float* W4    = (const float*)d_in[17];
  const float* b4    = (const float*)d_in[18];
  float* out = (float*)d_out;

  char* ws = (char*)d_ws;
  size_t off = 0;
  auto alloc = [&](size_t bytes) -> void* {
    void* p = ws + off;
    off += (bytes + 255) & ~(size_t)255;
    return p;
  };
  float* XL1  = (float*)alloc((size_t)Nn * 256 * 4);   // reused as XL2
  float* XR1  = (float*)alloc((size_t)Nn * 256 * 4);   // reused as XR2
  float* H1   = (float*)alloc((size_t)Nn * 256 * 4);
  unsigned short* PB1H = (unsigned short*)alloc((size_t)512 * Dd * 2);
  unsigned short* PB1L = (unsigned short*)alloc((size_t)512 * Dd * 2);
  unsigned short* PB2H = (unsigned short*)alloc((size_t)128 * 256 * 2);
  unsigned short* PB2L = (unsigned short*)alloc((size_t)128 * 256 * 2);
  int*   rowptr = (int*)alloc((size_t)(Nn + 1) * 4);
  int*   deg    = (int*)alloc((size_t)Nn * 4);
  int*   cursor = (int*)alloc((size_t)Nn * 4);
  int*   srcv   = (int*)alloc((size_t)ETOT * 4);
  float* H2   = (float*)alloc((size_t)Nn * 64 * 4);
  float* GP   = (float*)alloc((size_t)Gg * 64 * 4);
  int*   gs   = (int*)alloc((size_t)(Gg + 1) * 4);
  float* XL2 = XL1;
  float* XR2 = XR1;

  const int* srcA = ei;
  const int* dstA = ei + Ee;

  // CSR by destination (self-loop folded in via deg init = 1)
  fill_int<<<(Nn + 255) / 256, 256, 0, stream>>>(deg, Nn, 1);
  hist_dst<<<(Ee + 255) / 256, 256, 0, stream>>>(dstA, deg);
  scan_deg<<<1, 1024, 0, stream>>>(deg, rowptr, cursor);
  scatter_edges<<<(ETOT + 255) / 256, 256, 0, stream>>>(srcA, dstA, cursor, srcv);
  gbounds<<<1, 512, 0, stream>>>(batch, gs);

  // weight transposes + bf16 hi/lo splits into packed consumption-order layout
  wsplit<<<dim3(Dd / 32, 512 / 32), 256, 0, stream>>>(Wl1, Wr1, Dd, 256, Dd / 32, PB1H, PB1L);
  wsplit<<<dim3(256 / 32, 128 / 32), 256, 0, stream>>>(Wl2, Wr2, 256, 64, 256 / 32, PB2H, PB2L);

  // layer 1: X[20000x1280] @ W^T -> XL1|XR1 [20000x256 each]
  // 1-D grid, XCD swizzle: pad y-tiles (157) to 160 -> 640 ids
  gemm_2t<<<640, 512, 0, stream>>>(
      x, Dd, Dd / 32, 4, (Nn + 127) / 128, PB1H, PB1L, bl1, br1, 256, XL1, XR1);
  gat_fused1<<<(Nn + 3) / 4, 256, 0, stream>>>(rowptr, srcv, XL1, XR1, att1, bias1, H1);

  // layer 2: H1[20000x256] @ W2^T -> XL2|XR2 [20000x64 each]
  gemm_2t<<<(Nn + 127) / 128, 512, 0, stream>>>(
      H1, 256, 256 / 32, 1, (Nn + 127) / 128, PB2H, PB2L, bl2, br2, 64, XL2, XR2);
  gat_fused2<<<(Nn + 3) / 4, 256, 0, stream>>>(rowptr, srcv, XL2, XR2, att2, bias2, H2);

  // pool + head
  pool_seg<<<Gg, 64, 0, stream>>>(H2, gs, GP);
  mlp_head<<<Gg, 64, 0, stream>>>(GP, W3, b3, W4, b4, out);
}

// Round 7
// 452.927 us; speedup vs baseline: 1.4191x; 1.0290x over previous
//
#include <hip/hip_runtime.h>

constexpr int Nn    = 20000;
constexpr int Ee    = 320000;
constexpr int Dd    = 1280;
constexpr int Gg    = 256;
constexpr int ETOT  = Ee + Nn;
#define NEG 0.2f

typedef __attribute__((ext_vector_type(8))) short s8v;            // 8 bf16 = 4 VGPR
typedef __attribute__((ext_vector_type(8))) unsigned short u16x8;
typedef __attribute__((ext_vector_type(4))) float f4v;            // MFMA acc

__device__ inline float lrelu(float v){ return v > 0.f ? v : NEG * v; }
__device__ inline float wave_sum(float v){
  #pragma unroll
  for(int o = 32; o; o >>= 1) v += __shfl_xor(v, o, 64);
  return v;
}
__device__ inline unsigned short f2bf(float x){
  unsigned u = __float_as_uint(x);
  return (unsigned short)((u + 0x7FFFu + ((u >> 16) & 1u)) >> 16);   // RNE
}
__device__ inline float bf2f(unsigned short h){ return __uint_as_float(((unsigned)h) << 16); }

__device__ inline void async_cp16(const void* g, void* l){
  __builtin_amdgcn_global_load_lds((const __attribute__((address_space(1))) void*)g,
                                   (__attribute__((address_space(3))) void*)l, 16, 0, 0);
}

// packed-weight offset, consumption order: granule = [ntile][iter][gq*128 + n]
__device__ inline size_t pkoff(int n, int k, int NITp){
  return ((((size_t)(n >> 7) * NITp + (k >> 5)) * 512)
          + (((k >> 3) & 3) * 128 + (n & 127))) * 8 + (k & 7);
}

// ---------------- CSR build (by destination) ----------------
__global__ void fill_int(int* p, int n, int v){
  int i = blockIdx.x * blockDim.x + threadIdx.x;
  if(i < n) p[i] = v;
}
__global__ void hist_dst(const int* __restrict__ dst, int* __restrict__ deg){
  int e = blockIdx.x * blockDim.x + threadIdx.x;
  if(e < Ee) atomicAdd(&deg[dst[e]], 1);
}
__global__ __launch_bounds__(1024) void scan_deg(const int* __restrict__ deg,
                                                 int* __restrict__ rowptr,
                                                 int* __restrict__ cursor){
  __shared__ int part[1024];
  int t = threadIdx.x;
  const int CH = (Nn + 1023) / 1024;
  int base = t * CH;
  int s = 0;
  for(int j = 0; j < CH; j++){ int idx = base + j; if(idx < Nn) s += deg[idx]; }
  part[t] = s;
  __syncthreads();
  for(int off = 1; off < 1024; off <<= 1){
    int v = (t >= off) ? part[t - off] : 0;
    __syncthreads();
    part[t] += v;
    __syncthreads();
  }
  int acc = part[t] - s;
  for(int j = 0; j < CH; j++){
    int idx = base + j;
    if(idx < Nn){ rowptr[idx] = acc; cursor[idx] = acc; acc += deg[idx]; }
  }
  if(t == 1023) rowptr[Nn] = part[1023];
}
__global__ void scatter_edges(const int* __restrict__ src, const int* __restrict__ dst,
                              int* __restrict__ cursor, int* __restrict__ srcv){
  int e = blockIdx.x * blockDim.x + threadIdx.x;
  if(e >= ETOT) return;
  int d, s;
  if(e < Ee){ d = dst[e]; s = src[e]; } else { d = e - Ee; s = d; }
  int pos = atomicAdd(&cursor[d], 1);
  srcv[pos] = s;
}

// ------------- W split to packed layout: from Wl|Wr [K][Ca] -------------
__global__ __launch_bounds__(256) void wsplit(const float* __restrict__ Wl,
                                              const float* __restrict__ Wr,
                                              int K, int Ca, int NITp,
                                              unsigned short* __restrict__ PBH,
                                              unsigned short* __restrict__ PBL){
  __shared__ float t[32][33];
  int k0 = blockIdx.x * 32, n0 = blockIdx.y * 32;
  int tx = threadIdx.x & 31, ty = threadIdx.x >> 5;
  #pragma unroll
  for(int j = 0; j < 4; j++){
    int kk = ty + j * 8;
    int n = n0 + tx;
    t[kk][tx] = (n < Ca) ? Wl[(size_t)(k0 + kk) * Ca + n]
                         : Wr[(size_t)(k0 + kk) * Ca + (n - Ca)];
  }
  __syncthreads();
  #pragma unroll
  for(int j = 0; j < 4; j++){
    int nn = ty + j * 8;
    float v = t[tx][nn];
    unsigned short hi = f2bf(v);
    unsigned short lo = f2bf(v - bf2f(hi));
    size_t o = pkoff(n0 + nn, k0 + tx, NITp);
    PBH[o] = hi;
    PBL[o] = lo;
  }
}

// ------- layer-1 GEMM: split-bf16 2-term, tile 128x128, XL out bf16, XR fp32 -------
__global__ __launch_bounds__(512) void gemm_2t(
    const float* __restrict__ X, int K, int niter, int nty,
    const unsigned short* __restrict__ PBH, const unsigned short* __restrict__ PBL,
    const float* __restrict__ bl, const float* __restrict__ br,
    unsigned short* __restrict__ XLb, float* __restrict__ XR)
{
  int id = blockIdx.x;
  int g8 = id >> 5, rem = id & 31;
  int xb = rem >> 3, yb = g8 * 8 + (rem & 7);
  if(yb >= nty) return;

  __shared__ unsigned short sA [2][4096];
  __shared__ unsigned short sBh[2][4096];
  __shared__ unsigned short sBl[2][4096];

  const int tid  = threadIdx.x;
  const int lane = tid & 63;
  const int w    = tid >> 6;
  const int wm   = w & 1, wn = w >> 1;
  const int bm   = yb * 128;
  const int bn   = xb * 128;

  f4v acc[4][2] = {};

  const int ar = w * 16 + (lane >> 2);
  const int aq = lane & 3;
  int gmr = bm + ar; if(gmr >= Nn) gmr = Nn - 1;
  const float* aptr = X + (size_t)gmr * K + aq * 8;
  const int awoff = (aq * 128 + ((ar + aq * 4) & 127)) * 8;

  const size_t bbase = ((size_t)xb * niter) * 4096 + tid * 8;
  const unsigned short* bhp = PBH + bbase;
  const unsigned short* blp = PBL + bbase;
  const int bldsoff = w * 512;

  async_cp16(bhp, &sBh[0][bldsoff]);
  async_cp16(blp, &sBl[0][bldsoff]);
  {
    float4 v0 = *(const float4*)(aptr);
    float4 v1 = *(const float4*)(aptr + 4);
    float fv[8] = {v0.x, v0.y, v0.z, v0.w, v1.x, v1.y, v1.z, v1.w};
    u16x8 hv;
    #pragma unroll
    for(int q = 0; q < 8; q++) hv[q] = f2bf(fv[q]);
    *(u16x8*)&sA[0][awoff] = hv;
  }

  const int mr = lane & 15;
  const int gq = lane >> 4;
  int aoff[4], boff[2];
  #pragma unroll
  for(int i = 0; i < 4; i++){
    int row = wm * 64 + i * 16 + mr;
    aoff[i] = (gq * 128 + ((row + gq * 4) & 127)) * 8;
  }
  #pragma unroll
  for(int j = 0; j < 2; j++){
    int n = wn * 32 + j * 16 + mr;
    boff[j] = (gq * 128 + n) * 8;
  }

  for(int it = 0; it < niter; it++){
    const int cur = it & 1, nxt = cur ^ 1;
    __syncthreads();
    float4 v0, v1;
    const bool more = (it + 1 < niter);
    if(more){
      async_cp16(bhp + (size_t)(it + 1) * 4096, &sBh[nxt][bldsoff]);
      async_cp16(blp + (size_t)(it + 1) * 4096, &sBl[nxt][bldsoff]);
      v0 = *(const float4*)(aptr + (it + 1) * 32);
      v1 = *(const float4*)(aptr + (it + 1) * 32 + 4);
    }
    s8v ah[4];
    #pragma unroll
    for(int i = 0; i < 4; i++) ah[i] = *(const s8v*)&sA[cur][aoff[i]];
    #pragma unroll
    for(int j = 0; j < 2; j++){
      s8v bh  = *(const s8v*)&sBh[cur][boff[j]];
      s8v bl2 = *(const s8v*)&sBl[cur][boff[j]];
      #pragma unroll
      for(int i = 0; i < 4; i++){
        acc[i][j] = __builtin_amdgcn_mfma_f32_16x16x32_bf16(ah[i], bh,  acc[i][j], 0, 0, 0);
        acc[i][j] = __builtin_amdgcn_mfma_f32_16x16x32_bf16(ah[i], bl2, acc[i][j], 0, 0, 0);
      }
    }
    if(more){
      float fv[8] = {v0.x, v0.y, v0.z, v0.w, v1.x, v1.y, v1.z, v1.w};
      u16x8 hv;
      #pragma unroll
      for(int q = 0; q < 8; q++) hv[q] = f2bf(fv[q]);
      *(u16x8*)&sA[nxt][awoff] = hv;
    }
  }

  const int quad = lane >> 4, col = lane & 15;
  #pragma unroll
  for(int j = 0; j < 2; j++){
    int gn = bn + wn * 32 + j * 16 + col;
    #pragma unroll
    for(int i = 0; i < 4; i++){
      #pragma unroll
      for(int rg = 0; rg < 4; rg++){
        int gmm = bm + wm * 64 + i * 16 + quad * 4 + rg;
        if(gmm < Nn){
          float v = acc[i][j][rg];
          if(gn < 256) XLb[(size_t)gmm * 256 + gn] = f2bf(v + bl[gn]);
          else         XR [(size_t)gmm * 256 + (gn - 256)] = v + br[gn - 256];
        }
      }
    }
  }
}

// ------- layer-2 GEMM: A pre-packed bf16 (cp16 DMA), tile 64x128, K=256 -------
__global__ __launch_bounds__(512) void gemm2_cp(
    const unsigned short* __restrict__ PA,   // [ytile][8 iter][gq*64+row][8]
    const unsigned short* __restrict__ PBH, const unsigned short* __restrict__ PBL,
    const float* __restrict__ bl, const float* __restrict__ br,
    unsigned short* __restrict__ XLb, float* __restrict__ XR)
{
  const int yb = blockIdx.x;
  __shared__ unsigned short sA [2][2048];   // 256 granules x 16B
  __shared__ unsigned short sBh[2][4096];
  __shared__ unsigned short sBl[2][4096];

  const int tid  = threadIdx.x;
  const int lane = tid & 63;
  const int w    = tid >> 6;
  const int wm   = w & 1, wn = w >> 1;
  const int bm   = yb * 64;
  const int NIT  = 8;

  f4v acc[2][2] = {};

  const unsigned short* bhp = PBH + tid * 8;
  const unsigned short* blp = PBL + tid * 8;
  const int bldsoff = w * 512;
  const unsigned short* pap = PA + ((size_t)yb * NIT * 256 + tid) * 8;
  const int aldsoff = w * 512;   // waves 0..3 cover 256 granules

  async_cp16(bhp, &sBh[0][bldsoff]);
  async_cp16(blp, &sBl[0][bldsoff]);
  if(w < 4) async_cp16(pap, &sA[0][aldsoff]);

  const int mr = lane & 15;
  const int gq = lane >> 4;
  int aoff[2], boff[2];
  #pragma unroll
  for(int i = 0; i < 2; i++) aoff[i] = (gq * 64 + wm * 32 + i * 16 + mr) * 8;
  #pragma unroll
  for(int j = 0; j < 2; j++) boff[j] = (gq * 128 + wn * 32 + j * 16 + mr) * 8;

  for(int it = 0; it < NIT; it++){
    const int cur = it & 1, nxt = cur ^ 1;
    __syncthreads();
    if(it + 1 < NIT){
      async_cp16(bhp + (size_t)(it + 1) * 4096, &sBh[nxt][bldsoff]);
      async_cp16(blp + (size_t)(it + 1) * 4096, &sBl[nxt][bldsoff]);
      if(w < 4) async_cp16(pap + (size_t)(it + 1) * 2048, &sA[nxt][aldsoff]);
    }
    s8v ah[2];
    #pragma unroll
    for(int i = 0; i < 2; i++) ah[i] = *(const s8v*)&sA[cur][aoff[i]];
    #pragma unroll
    for(int j = 0; j < 2; j++){
      s8v bh  = *(const s8v*)&sBh[cur][boff[j]];
      s8v bl2 = *(const s8v*)&sBl[cur][boff[j]];
      #pragma unroll
      for(int i = 0; i < 2; i++){
        acc[i][j] = __builtin_amdgcn_mfma_f32_16x16x32_bf16(ah[i], bh,  acc[i][j], 0, 0, 0);
        acc[i][j] = __builtin_amdgcn_mfma_f32_16x16x32_bf16(ah[i], bl2, acc[i][j], 0, 0, 0);
      }
    }
  }

  const int quad = lane >> 4, col = lane & 15;
  #pragma unroll
  for(int j = 0; j < 2; j++){
    int gn = wn * 32 + j * 16 + col;          // 0..127
    #pragma unroll
    for(int i = 0; i < 2; i++){
      #pragma unroll
      for(int rg = 0; rg < 4; rg++){
        int gmm = bm + wm * 32 + i * 16 + quad * 4 + rg;
        if(gmm < Nn){
          float v = acc[i][j][rg];
          if(gn < 64) XLb[(size_t)gmm * 64 + gn] = f2bf(v + bl[gn]);
          else        XR [(size_t)gmm * 64 + (gn - 64)] = v + br[gn - 64];
        }
      }
    }
  }
}

// -------- fused GATv2 layer 1: wave/node, bf16 XL gathers, packed bf16 H out --------
__global__ __launch_bounds__(256) void gat_fused1(
    const int* __restrict__ rowptr, const int* __restrict__ srcv,
    const unsigned short* __restrict__ XLb, const float* __restrict__ XR,
    const float* __restrict__ att, const float* __restrict__ bias,
    unsigned short* __restrict__ PA2)
{
  int node = blockIdx.x * 4 + (threadIdx.x >> 6);
  int lane = threadIdx.x & 63;
  if(node >= Nn) return;
  const float4 xr = *(const float4*)(XR + (size_t)node * 256 + lane * 4);
  const float4 a  = *(const float4*)(att + lane * 4);
  int r0 = rowptr[node], r1 = rowptr[node + 1];
  float m[4], l[4]; float4 acc[4];
  #pragma unroll
  for(int c = 0; c < 4; c++){ m[c] = -1e30f; l[c] = 0.f; acc[c] = make_float4(0,0,0,0); }
  for(int k = r0; k < r1; k += 4){
    int nv = r1 - k;
    int s[4]; float4 xl[4]; float p[4];
    #pragma unroll
    for(int c = 0; c < 4; c++){
      int kk = (c < nv) ? (k + c) : k;
      s[c] = srcv[kk];
    }
    #pragma unroll
    for(int c = 0; c < 4; c++){
      ushort4 u = *(const ushort4*)(XLb + (size_t)s[c] * 256 + lane * 4);
      xl[c] = make_float4(bf2f(u.x), bf2f(u.y), bf2f(u.z), bf2f(u.w));
    }
    #pragma unroll
    for(int c = 0; c < 4; c++){
      p[c] = lrelu(xl[c].x + xr.x) * a.x + lrelu(xl[c].y + xr.y) * a.y
           + lrelu(xl[c].z + xr.z) * a.z + lrelu(xl[c].w + xr.w) * a.w;
    }
    #pragma unroll
    for(int o = 8; o; o >>= 1){
      #pragma unroll
      for(int c = 0; c < 4; c++) p[c] += __shfl_xor(p[c], o, 64);
    }
    #pragma unroll
    for(int c = 0; c < 4; c++){
      if(c < nv){
        float mn = fmaxf(m[c], p[c]);
        float sc = __expf(m[c] - mn);
        float wg = __expf(p[c] - mn);
        l[c] = l[c] * sc + wg;
        acc[c].x = acc[c].x * sc + wg * xl[c].x;
        acc[c].y = acc[c].y * sc + wg * xl[c].y;
        acc[c].z = acc[c].z * sc + wg * xl[c].z;
        acc[c].w = acc[c].w * sc + wg * xl[c].w;
        m[c] = mn;
      }
    }
  }
  float M = fmaxf(fmaxf(m[0], m[1]), fmaxf(m[2], m[3]));
  float L = 0.f; float4 A4 = make_float4(0,0,0,0);
  #pragma unroll
  for(int c = 0; c < 4; c++){
    float sc = __expf(m[c] - M);
    L += l[c] * sc;
    A4.x += acc[c].x * sc; A4.y += acc[c].y * sc;
    A4.z += acc[c].z * sc; A4.w += acc[c].w * sc;
  }
  float inv = 1.f / (L + 1e-16f);
  const float4 b = *(const float4*)(bias + lane * 4);
  float4 o;
  o.x = fmaxf(A4.x * inv + b.x, 0.f);
  o.y = fmaxf(A4.y * inv + b.y, 0.f);
  o.z = fmaxf(A4.z * inv + b.z, 0.f);
  o.w = fmaxf(A4.w * inv + b.w, 0.f);
  // write H directly in gemm2's packed A order: ch = lane*4
  size_t po = ((((size_t)(node >> 6) * 8 + (lane >> 3)) * 256)
               + ((lane >> 1) & 3) * 64 + (node & 63)) * 8 + (lane & 1) * 4;
  *(ushort4*)(PA2 + po) = make_ushort4(f2bf(o.x), f2bf(o.y), f2bf(o.z), f2bf(o.w));
}

// -------- fused GATv2 layer 2: wave/node, heads=1, bf16 XL gathers --------
__global__ __launch_bounds__(256) void gat_fused2(
    const int* __restrict__ rowptr, const int* __restrict__ srcv,
    const unsigned short* __restrict__ XLb, const float* __restrict__ XR,
    const float* __restrict__ att, const float* __restrict__ bias,
    float* __restrict__ H)
{
  int node = blockIdx.x * 4 + (threadIdx.x >> 6);
  int lane = threadIdx.x & 63;
  if(node >= Nn) return;
  const float xr = XR[(size_t)node * 64 + lane];
  const float a = att[lane];
  int r0 = rowptr[node], r1 = rowptr[node + 1];
  float m[4], l[4], acc[4];
  #pragma unroll
  for(int c = 0; c < 4; c++){ m[c] = -1e30f; l[c] = 0.f; acc[c] = 0.f; }
  for(int k = r0; k < r1; k += 4){
    int nv = r1 - k;
    int s[4]; float xl[4]; float p[4];
    #pragma unroll
    for(int c = 0; c < 4; c++){
      int kk = (c < nv) ? (k + c) : k;
      s[c] = srcv[kk];
    }
    #pragma unroll
    for(int c = 0; c < 4; c++) xl[c] = bf2f(XLb[(size_t)s[c] * 64 + lane]);
    #pragma unroll
    for(int c = 0; c < 4; c++) p[c] = lrelu(xl[c] + xr) * a;
    #pragma unroll
    for(int o = 32; o; o >>= 1){
      #pragma unroll
      for(int c = 0; c < 4; c++) p[c] += __shfl_xor(p[c], o, 64);
    }
    #pragma unroll
    for(int c = 0; c < 4; c++){
      if(c < nv){
        float mn = fmaxf(m[c], p[c]);
        float sc = __expf(m[c] - mn);
        float wg = __expf(p[c] - mn);
        l[c] = l[c] * sc + wg;
        acc[c] = acc[c] * sc + wg * xl[c];
        m[c] = mn;
      }
    }
  }
  float M = fmaxf(fmaxf(m[0], m[1]), fmaxf(m[2], m[3]));
  float L = 0.f, A1 = 0.f;
  #pragma unroll
  for(int c = 0; c < 4; c++){
    float sc = __expf(m[c] - M);
    L += l[c] * sc; A1 += acc[c] * sc;
  }
  float inv = 1.f / (L + 1e-16f);
  H[(size_t)node * 64 + lane] = fmaxf(A1 * inv + bias[lane], 0.f);
}

// ---------------- group bounds + fused pool+MLP head ----------------
__global__ void gbounds(const int* __restrict__ batch, int* __restrict__ gs){
  int g = blockIdx.x * blockDim.x + threadIdx.x;
  if(g > Gg) return;
  int lo = 0, hi = Nn;
  while(lo < hi){ int mid = (lo + hi) >> 1; if(batch[mid] < g) lo = mid + 1; else hi = mid; }
  gs[g] = lo;
}
__global__ __launch_bounds__(64) void pool_mlp(const float* __restrict__ H2,
                                               const int* __restrict__ gs,
                                               const float* __restrict__ W3,
                                               const float* __restrict__ b3,
                                               const float* __restrict__ W4,
                                               const float* __restrict__ b4,
                                               float* __restrict__ out){
  int g = blockIdx.x, t = threadIdx.x;
  int i0 = gs[g], i1 = gs[g + 1];
  float a0 = 0.f, a1 = 0.f, a2 = 0.f, a3 = 0.f;
  int i = i0;
  for(; i + 3 < i1; i += 4){
    a0 += H2[(size_t)i * 64 + t];       a1 += H2[(size_t)(i + 1) * 64 + t];
    a2 += H2[(size_t)(i + 2) * 64 + t]; a3 += H2[(size_t)(i + 3) * 64 + t];
  }
  for(; i < i1; i++) a0 += H2[(size_t)i * 64 + t];
  __shared__ float sh[64];
  sh[t] = (a0 + a1) + (a2 + a3);
  __syncthreads();
  float acc = b3[t];
  #pragma unroll
  for(int k = 0; k < 64; k++) acc = fmaf(sh[k], W3[k * 64 + t], acc);
  acc = fmaxf(acc, 0.f);
  float p = acc * W4[t];
  p = wave_sum(p);
  if(t == 0) out[g] = p + b4[0];
}

extern "C" void kernel_launch(void* const* d_in, const int* in_sizes, int n_in,
                              void* d_out, int out_size, void* d_ws, size_t ws_size,
                              hipStream_t stream)
{
  const float* x     = (const float*)d_in[0];
  const int*   ei    = (const int*)d_in[1];
  const int*   batch = (const int*)d_in[2];
  const float* Wl1   = (const float*)d_in[3];
  const float* bl1   = (const float*)d_in[4];
  const float* Wr1   = (const float*)d_in[5];
  const float* br1   = (const float*)d_in[6];
  const float* att1  = (const float*)d_in[7];
  const float* bias1 = (const float*)d_in[8];
  const float* Wl2   = (const float*)d_in[9];
  const float* bl2   = (const float*)d_in[10];
  const float* Wr2   = (const float*)d_in[11];
  const float* br2   = (const float*)d_in[12];
  const float* att2  = (const float*)d_in[13];
  const float* bias2 = (const float*)d_in[14];
  const float* W3    = (const float*)d_in[15];
  const float* b3    = (const float*)d_in[16];
  const float* W4    = (const float*)d_in[17];
  const float* b4    = (const float*)d_in[18];
  float* out = (float*)d_out;

  char* ws = (char*)d_ws;
  size_t off = 0;
  auto alloc = [&](size_t bytes) -> void* {
    void* p = ws + off;
    off += (bytes + 255) & ~(size_t)255;
    return p;
  };
  const int NTY1 = (Nn + 127) / 128;       // 157
  const int NTY2 = (Nn + 63) / 64;         // 313
  unsigned short* XLb1 = (unsigned short*)alloc((size_t)Nn * 256 * 2);   // 10.24 MB
  float*          XR1  = (float*)alloc((size_t)Nn * 256 * 4);            // 20.48 MB
  unsigned short* PA2  = (unsigned short*)alloc((size_t)NTY2 * 8 * 256 * 8 * 2); // 10.3 MB
  unsigned short* XLb2 = (unsigned short*)alloc((size_t)Nn * 64 * 2);    // 2.56 MB
  float*          XR2  = (float*)alloc((size_t)Nn * 64 * 4);             // 5.12 MB
  unsigned short* PB1H = (unsigned short*)alloc((size_t)512 * Dd * 2);
  unsigned short* PB1L = (unsigned short*)alloc((size_t)512 * Dd * 2);
  unsigned short* PB2H = (unsigned short*)alloc((size_t)128 * 256 * 2);
  unsigned short* PB2L = (unsigned short*)alloc((size_t)128 * 256 * 2);
  int*   rowptr = (int*)alloc((size_t)(Nn + 1) * 4);
  int*   deg    = (int*)alloc((size_t)Nn * 4);
  int*   cursor = (int*)alloc((size_t)Nn * 4);
  int*   srcv   = (int*)alloc((size_t)ETOT * 4);
  float* H2   = (float*)alloc((size_t)Nn * 64 * 4);
  int*   gs   = (int*)alloc((size_t)(Gg + 1) * 4);

  const int* srcA = ei;
  const int* dstA = ei + Ee;

  // CSR by destination (self-loop folded in via deg init = 1)
  fill_int<<<(Nn + 255) / 256, 256, 0, stream>>>(deg, Nn, 1);
  hist_dst<<<(Ee + 255) / 256, 256, 0, stream>>>(dstA, deg);
  scan_deg<<<1, 1024, 0, stream>>>(deg, rowptr, cursor);
  scatter_edges<<<(ETOT + 255) / 256, 256, 0, stream>>>(srcA, dstA, cursor, srcv);
  gbounds<<<1, 512, 0, stream>>>(batch, gs);

  // weight splits into packed consumption-order layout
  wsplit<<<dim3(Dd / 32, 512 / 32), 256, 0, stream>>>(Wl1, Wr1, Dd, 256, Dd / 32, PB1H, PB1L);
  wsplit<<<dim3(256 / 32, 128 / 32), 256, 0, stream>>>(Wl2, Wr2, 256, 64, 256 / 32, PB2H, PB2L);

  // layer 1: X @ W1^T -> XLb1 (bf16) | XR1 (fp32); XCD-swizzled 1-D grid
  gemm_2t<<<640, 512, 0, stream>>>(
      x, Dd, Dd / 32, NTY1, PB1H, PB1L, bl1, br1, XLb1, XR1);
  gat_fused1<<<(Nn + 3) / 4, 256, 0, stream>>>(rowptr, srcv, XLb1, XR1, att1, bias1, PA2);

  // layer 2: PA2 @ W2^T -> XLb2 (bf16) | XR2 (fp32)
  gemm2_cp<<<NTY2, 512, 0, stream>>>(PA2, PB2H, PB2L, bl2, br2, XLb2, XR2);
  gat_fused2<<<(Nn + 3) / 4, 256, 0, stream>>>(rowptr, srcv, XLb2, XR2, att2, bias2, H2);

  // pool + head (fused)
  pool_mlp<<<Gg, 64, 0, stream>>>(H2, gs, W3, b3, W4, b4, out);
}

// Round 8
// 393.585 us; speedup vs baseline: 1.6330x; 1.1508x over previous
//
#include <hip/hip_runtime.h>

constexpr int Nn    = 20000;
constexpr int Ee    = 320000;
constexpr int Dd    = 1280;
constexpr int Gg    = 256;
constexpr int ETOT  = Ee + Nn;
#define NEG 0.2f

typedef __attribute__((ext_vector_type(8))) short s8v;            // 8 bf16 = 4 VGPR
typedef __attribute__((ext_vector_type(8))) unsigned short u16x8;
typedef __attribute__((ext_vector_type(4))) float f4v;            // MFMA acc

constexpr int NTY1 = (Nn + 127) / 128;     // 157 row-tiles (layer1)
constexpr int NIT1 = Dd / 32;              // 40 k-iters (layer1)
constexpr int NTY2 = (Nn + 63) / 64;       // 313 row-tiles (layer2)

// K1 mega-kernel block ranges
constexpr int NP1 = NTY1 * NIT1;           // 6280 prepack blocks
constexpr int NH  = (Ee + 255) / 256;      // 1250 hist blocks
constexpr int NW1 = (Dd / 32) * (512 / 32);        // 640 wsplit1
constexpr int NW2 = (256 / 32) * (128 / 32);       // 32 wsplit2
constexpr int NG  = 2;                     // gbounds
constexpr int K1B = NP1 + NH + NW1 + NW2 + NG;

// K2 (gemm1 + scatter) block ranges
constexpr int NGEMM = 640;
constexpr int NSC   = (ETOT + 511) / 512;  // 665
constexpr int K2B   = NGEMM + NSC;

__device__ inline float lrelu(float v){ return v > 0.f ? v : NEG * v; }
__device__ inline float wave_sum(float v){
  #pragma unroll
  for(int o = 32; o; o >>= 1) v += __shfl_xor(v, o, 64);
  return v;
}
__device__ inline unsigned short f2bf(float x){
  unsigned u = __float_as_uint(x);
  return (unsigned short)((u + 0x7FFFu + ((u >> 16) & 1u)) >> 16);   // RNE
}
__device__ inline float bf2f(unsigned short h){ return __uint_as_float(((unsigned)h) << 16); }

__device__ inline void async_cp16(const void* g, void* l){
  __builtin_amdgcn_global_load_lds((const __attribute__((address_space(1))) void*)g,
                                   (__attribute__((address_space(3))) void*)l, 16, 0, 0);
}

// packed-weight offset, consumption order: granule = [ntile][iter][gq*128 + n]
__device__ inline size_t pkoff(int n, int k, int NITp){
  return ((((size_t)(n >> 7) * NITp + (k >> 5)) * 512)
          + (((k >> 3) & 3) * 128 + (n & 127))) * 8 + (k & 7);
}

// ================= K1 mega-kernel: prepack | hist | wsplit1 | wsplit2 | gbounds =================
__global__ __launch_bounds__(256) void k1_mega(
    const float* __restrict__ X, unsigned short* __restrict__ PA1,
    const int* __restrict__ dstA, int* __restrict__ deg,
    const float* __restrict__ Wl1, const float* __restrict__ Wr1,
    unsigned short* __restrict__ PB1H, unsigned short* __restrict__ PB1L,
    const float* __restrict__ Wl2, const float* __restrict__ Wr2,
    unsigned short* __restrict__ PB2H, unsigned short* __restrict__ PB2L,
    const int* __restrict__ batch, int* __restrict__ gs)
{
  const int bid = blockIdx.x;
  const int tid = threadIdx.x;

  if(bid < NP1){
    // ---- prepack X -> bf16 A granules [yb][it][gq*128+row][8] ----
    int yb = bid / NIT1, it = bid % NIT1;
    int row = tid >> 1, half = tid & 1;
    int r = yb * 128 + row; if(r >= Nn) r = Nn - 1;
    const float* xp = X + (size_t)r * Dd + it * 32 + half * 16;
    float4 v0 = *(const float4*)(xp);
    float4 v1 = *(const float4*)(xp + 4);
    float4 v2 = *(const float4*)(xp + 8);
    float4 v3 = *(const float4*)(xp + 12);
    float fv[16] = {v0.x,v0.y,v0.z,v0.w, v1.x,v1.y,v1.z,v1.w,
                    v2.x,v2.y,v2.z,v2.w, v3.x,v3.y,v3.z,v3.w};
    size_t base = ((size_t)bid) * 512;
    #pragma unroll
    for(int g2 = 0; g2 < 2; g2++){
      int gq = half * 2 + g2;
      u16x8 hv;
      #pragma unroll
      for(int q = 0; q < 8; q++) hv[q] = f2bf(fv[g2 * 8 + q]);
      *(u16x8*)(PA1 + (base + gq * 128 + row) * 8) = hv;
    }
    return;
  }
  if(bid < NP1 + NH){
    int e = (bid - NP1) * 256 + tid;
    if(e < Ee) atomicAdd(&deg[dstA[e]], 1);
    return;
  }
  if(bid < NP1 + NH + NW1 + NW2){
    // ---- wsplit (layer 1 or 2) ----
    const float *Wl, *Wr; unsigned short *PH, *PL; int K, Ca, idx;
    if(bid < NP1 + NH + NW1){ Wl = Wl1; Wr = Wr1; PH = PB1H; PL = PB1L; K = Dd;  Ca = 256; idx = bid - (NP1 + NH); }
    else                    { Wl = Wl2; Wr = Wr2; PH = PB2H; PL = PB2L; K = 256; Ca = 64;  idx = bid - (NP1 + NH + NW1); }
    int nk = K / 32;
    int k0 = (idx % nk) * 32, n0 = (idx / nk) * 32;
    __shared__ float t[32][33];
    int tx = tid & 31, ty = tid >> 5;
    #pragma unroll
    for(int j = 0; j < 4; j++){
      int kk = ty + j * 8;
      int n = n0 + tx;
      t[kk][tx] = (n < Ca) ? Wl[(size_t)(k0 + kk) * Ca + n]
                           : Wr[(size_t)(k0 + kk) * Ca + (n - Ca)];
    }
    __syncthreads();
    #pragma unroll
    for(int j = 0; j < 4; j++){
      int nn = ty + j * 8;
      float v = t[tx][nn];
      unsigned short hi = f2bf(v);
      unsigned short lo = f2bf(v - bf2f(hi));
      size_t o = pkoff(n0 + nn, k0 + tx, nk);
      PH[o] = hi;
      PL[o] = lo;
    }
    return;
  }
  {
    // ---- gbounds ----
    int g = (bid - (NP1 + NH + NW1 + NW2)) * 256 + tid;
    if(g > Gg) return;
    int lo = 0, hi = Nn;
    while(lo < hi){ int mid = (lo + hi) >> 1; if(batch[mid] < g) lo = mid + 1; else hi = mid; }
    gs[g] = lo;
  }
}

// ================= scan (self-loop +1 folded in) =================
__global__ __launch_bounds__(1024) void scan_deg(const int* __restrict__ deg,
                                                 int* __restrict__ rowptr,
                                                 int* __restrict__ cursor){
  __shared__ int part[1024];
  int t = threadIdx.x;
  const int CH = (Nn + 1023) / 1024;
  int base = t * CH;
  int s = 0;
  for(int j = 0; j < CH; j++){ int idx = base + j; if(idx < Nn) s += deg[idx] + 1; }
  part[t] = s;
  __syncthreads();
  for(int off = 1; off < 1024; off <<= 1){
    int v = (t >= off) ? part[t - off] : 0;
    __syncthreads();
    part[t] += v;
    __syncthreads();
  }
  int acc = part[t] - s;
  for(int j = 0; j < CH; j++){
    int idx = base + j;
    if(idx < Nn){ rowptr[idx] = acc; cursor[idx] = acc; acc += deg[idx] + 1; }
  }
  if(t == 1023) rowptr[Nn] = part[1023];
}

// ================= K2: gemm1 (pure-DMA staging) | scatter =================
__global__ __launch_bounds__(512) void k2_gemm_scatter(
    const unsigned short* __restrict__ PA1,
    const unsigned short* __restrict__ PBH, const unsigned short* __restrict__ PBL,
    const float* __restrict__ bl, const float* __restrict__ br,
    unsigned short* __restrict__ XLb, float* __restrict__ XR,
    const int* __restrict__ srcA, const int* __restrict__ dstA,
    int* __restrict__ cursor, int* __restrict__ srcv)
{
  __shared__ unsigned short sA [2][4096];
  __shared__ unsigned short sBh[2][4096];
  __shared__ unsigned short sBl[2][4096];

  if(blockIdx.x >= NGEMM){
    int e = (blockIdx.x - NGEMM) * 512 + threadIdx.x;
    if(e >= ETOT) return;
    int d, s;
    if(e < Ee){ d = dstA[e]; s = srcA[e]; } else { d = e - Ee; s = d; }
    int pos = atomicAdd(&cursor[d], 1);
    srcv[pos] = s;
    return;
  }

  int id = blockIdx.x;
  int g8 = id >> 5, rem = id & 31;
  int xb = rem >> 3, yb = g8 * 8 + (rem & 7);
  if(yb >= NTY1) return;

  const int tid  = threadIdx.x;
  const int lane = tid & 63;
  const int w    = tid >> 6;
  const int wm   = w & 1, wn = w >> 1;
  const int bm   = yb * 128;
  const int bn   = xb * 128;

  f4v acc[4][2] = {};

  // A staging: pure DMA, chunk = tid, contiguous 8 KB per iter
  const unsigned short* pap = PA1 + ((size_t)yb * NIT1 * 512 + tid) * 8;
  // B staging: chunk = tid, contiguous per iter
  const size_t bbase = ((size_t)xb * NIT1) * 4096 + tid * 8;
  const unsigned short* bhp = PBH + bbase;
  const unsigned short* blp = PBL + bbase;
  const int ldsoff = w * 512;    // wave-uniform dest base (+ lane*16B implicit)

  async_cp16(pap, &sA [0][ldsoff]);
  async_cp16(bhp, &sBh[0][ldsoff]);
  async_cp16(blp, &sBl[0][ldsoff]);

  const int mr = lane & 15;
  const int gq = lane >> 4;
  int aoff[4], boff[2];
  #pragma unroll
  for(int i = 0; i < 4; i++) aoff[i] = (gq * 128 + wm * 64 + i * 16 + mr) * 8;
  #pragma unroll
  for(int j = 0; j < 2; j++) boff[j] = (gq * 128 + wn * 32 + j * 16 + mr) * 8;

  for(int it = 0; it < NIT1; it++){
    const int cur = it & 1, nxt = cur ^ 1;
    __syncthreads();
    if(it + 1 < NIT1){
      async_cp16(pap + (size_t)(it + 1) * 4096, &sA [nxt][ldsoff]);
      async_cp16(bhp + (size_t)(it + 1) * 4096, &sBh[nxt][ldsoff]);
      async_cp16(blp + (size_t)(it + 1) * 4096, &sBl[nxt][ldsoff]);
    }
    s8v ah[4];
    #pragma unroll
    for(int i = 0; i < 4; i++) ah[i] = *(const s8v*)&sA[cur][aoff[i]];
    #pragma unroll
    for(int j = 0; j < 2; j++){
      s8v bh  = *(const s8v*)&sBh[cur][boff[j]];
      s8v bl2 = *(const s8v*)&sBl[cur][boff[j]];
      #pragma unroll
      for(int i = 0; i < 4; i++){
        acc[i][j] = __builtin_amdgcn_mfma_f32_16x16x32_bf16(ah[i], bh,  acc[i][j], 0, 0, 0);
        acc[i][j] = __builtin_amdgcn_mfma_f32_16x16x32_bf16(ah[i], bl2, acc[i][j], 0, 0, 0);
      }
    }
  }

  const int quad = lane >> 4, col = lane & 15;
  #pragma unroll
  for(int j = 0; j < 2; j++){
    int gn = bn + wn * 32 + j * 16 + col;
    #pragma unroll
    for(int i = 0; i < 4; i++){
      #pragma unroll
      for(int rg = 0; rg < 4; rg++){
        int gmm = bm + wm * 64 + i * 16 + quad * 4 + rg;
        if(gmm < Nn){
          float v = acc[i][j][rg];
          if(gn < 256) XLb[(size_t)gmm * 256 + gn] = f2bf(v + bl[gn]);
          else         XR [(size_t)gmm * 256 + (gn - 256)] = v + br[gn - 256];
        }
      }
    }
  }
}

// ------- layer-2 GEMM: A pre-packed bf16 (cp16 DMA), tile 64x128, K=256 -------
__global__ __launch_bounds__(512) void gemm2_cp(
    const unsigned short* __restrict__ PA,
    const unsigned short* __restrict__ PBH, const unsigned short* __restrict__ PBL,
    const float* __restrict__ bl, const float* __restrict__ br,
    unsigned short* __restrict__ XLb, float* __restrict__ XR)
{
  const int yb = blockIdx.x;
  __shared__ unsigned short sA [2][2048];
  __shared__ unsigned short sBh[2][4096];
  __shared__ unsigned short sBl[2][4096];

  const int tid  = threadIdx.x;
  const int lane = tid & 63;
  const int w    = tid >> 6;
  const int wm   = w & 1, wn = w >> 1;
  const int bm   = yb * 64;
  const int NIT  = 8;

  f4v acc[2][2] = {};

  const unsigned short* bhp = PBH + tid * 8;
  const unsigned short* blp = PBL + tid * 8;
  const int bldsoff = w * 512;
  const unsigned short* pap = PA + ((size_t)yb * NIT * 256 + tid) * 8;
  const int aldsoff = w * 512;

  async_cp16(bhp, &sBh[0][bldsoff]);
  async_cp16(blp, &sBl[0][bldsoff]);
  if(w < 4) async_cp16(pap, &sA[0][aldsoff]);

  const int mr = lane & 15;
  const int gq = lane >> 4;
  int aoff[2], boff[2];
  #pragma unroll
  for(int i = 0; i < 2; i++) aoff[i] = (gq * 64 + wm * 32 + i * 16 + mr) * 8;
  #pragma unroll
  for(int j = 0; j < 2; j++) boff[j] = (gq * 128 + wn * 32 + j * 16 + mr) * 8;

  for(int it = 0; it < NIT; it++){
    const int cur = it & 1, nxt = cur ^ 1;
    __syncthreads();
    if(it + 1 < NIT){
      async_cp16(bhp + (size_t)(it + 1) * 4096, &sBh[nxt][bldsoff]);
      async_cp16(blp + (size_t)(it + 1) * 4096, &sBl[nxt][bldsoff]);
      if(w < 4) async_cp16(pap + (size_t)(it + 1) * 2048, &sA[nxt][aldsoff]);
    }
    s8v ah[2];
    #pragma unroll
    for(int i = 0; i < 2; i++) ah[i] = *(const s8v*)&sA[cur][aoff[i]];
    #pragma unroll
    for(int j = 0; j < 2; j++){
      s8v bh  = *(const s8v*)&sBh[cur][boff[j]];
      s8v bl2 = *(const s8v*)&sBl[cur][boff[j]];
      #pragma unroll
      for(int i = 0; i < 2; i++){
        acc[i][j] = __builtin_amdgcn_mfma_f32_16x16x32_bf16(ah[i], bh,  acc[i][j], 0, 0, 0);
        acc[i][j] = __builtin_amdgcn_mfma_f32_16x16x32_bf16(ah[i], bl2, acc[i][j], 0, 0, 0);
      }
    }
  }

  const int quad = lane >> 4, col = lane & 15;
  #pragma unroll
  for(int j = 0; j < 2; j++){
    int gn = wn * 32 + j * 16 + col;
    #pragma unroll
    for(int i = 0; i < 2; i++){
      #pragma unroll
      for(int rg = 0; rg < 4; rg++){
        int gmm = bm + wm * 32 + i * 16 + quad * 4 + rg;
        if(gmm < Nn){
          float v = acc[i][j][rg];
          if(gn < 64) XLb[(size_t)gmm * 64 + gn] = f2bf(v + bl[gn]);
          else        XR [(size_t)gmm * 64 + (gn - 64)] = v + br[gn - 64];
        }
      }
    }
  }
}

// -------- fused GATv2 layer 1: wave/node, bf16 XL gathers, packed bf16 H out --------
__global__ __launch_bounds__(256) void gat_fused1(
    const int* __restrict__ rowptr, const int* __restrict__ srcv,
    const unsigned short* __restrict__ XLb, const float* __restrict__ XR,
    const float* __restrict__ att, const float* __restrict__ bias,
    unsigned short* __restrict__ PA2)
{
  int node = blockIdx.x * 4 + (threadIdx.x >> 6);
  int lane = threadIdx.x & 63;
  if(node >= Nn) return;
  const float4 xr = *(const float4*)(XR + (size_t)node * 256 + lane * 4);
  const float4 a  = *(const float4*)(att + lane * 4);
  int r0 = rowptr[node], r1 = rowptr[node + 1];
  float m[4], l[4]; float4 acc[4];
  #pragma unroll
  for(int c = 0; c < 4; c++){ m[c] = -1e30f; l[c] = 0.f; acc[c] = make_float4(0,0,0,0); }
  for(int k = r0; k < r1; k += 4){
    int nv = r1 - k;
    int s[4]; float4 xl[4]; float p[4];
    #pragma unroll
    for(int c = 0; c < 4; c++){
      int kk = (c < nv) ? (k + c) : k;
      s[c] = srcv[kk];
    }
    #pragma unroll
    for(int c = 0; c < 4; c++){
      ushort4 u = *(const ushort4*)(XLb + (size_t)s[c] * 256 + lane * 4);
      xl[c] = make_float4(bf2f(u.x), bf2f(u.y), bf2f(u.z), bf2f(u.w));
    }
    #pragma unroll
    for(int c = 0; c < 4; c++){
      p[c] = lrelu(xl[c].x + xr.x) * a.x + lrelu(xl[c].y + xr.y) * a.y
           + lrelu(xl[c].z + xr.z) * a.z + lrelu(xl[c].w + xr.w) * a.w;
    }
    #pragma unroll
    for(int o = 8; o; o >>= 1){
      #pragma unroll
      for(int c = 0; c < 4; c++) p[c] += __shfl_xor(p[c], o, 64);
    }
    #pragma unroll
    for(int c = 0; c < 4; c++){
      if(c < nv){
        float mn = fmaxf(m[c], p[c]);
        float sc = __expf(m[c] - mn);
        float wg = __expf(p[c] - mn);
        l[c] = l[c] * sc + wg;
        acc[c].x = acc[c].x * sc + wg * xl[c].x;
        acc[c].y = acc[c].y * sc + wg * xl[c].y;
        acc[c].z = acc[c].z * sc + wg * xl[c].z;
        acc[c].w = acc[c].w * sc + wg * xl[c].w;
        m[c] = mn;
      }
    }
  }
  float M = fmaxf(fmaxf(m[0], m[1]), fmaxf(m[2], m[3]));
  float L = 0.f; float4 A4 = make_float4(0,0,0,0);
  #pragma unroll
  for(int c = 0; c < 4; c++){
    float sc = __expf(m[c] - M);
    L += l[c] * sc;
    A4.x += acc[c].x * sc; A4.y += acc[c].y * sc;
    A4.z += acc[c].z * sc; A4.w += acc[c].w * sc;
  }
  float inv = 1.f / (L + 1e-16f);
  const float4 b = *(const float4*)(bias + lane * 4);
  float4 o;
  o.x = fmaxf(A4.x * inv + b.x, 0.f);
  o.y = fmaxf(A4.y * inv + b.y, 0.f);
  o.z = fmaxf(A4.z * inv + b.z, 0.f);
  o.w = fmaxf(A4.w * inv + b.w, 0.f);
  size_t po = ((((size_t)(node >> 6) * 8 + (lane >> 3)) * 256)
               + ((lane >> 1) & 3) * 64 + (node & 63)) * 8 + (lane & 1) * 4;
  *(ushort4*)(PA2 + po) = make_ushort4(f2bf(o.x), f2bf(o.y), f2bf(o.z), f2bf(o.w));
}

// -------- fused GATv2 layer 2: wave/node, heads=1, bf16 XL gathers --------
__global__ __launch_bounds__(256) void gat_fused2(
    const int* __restrict__ rowptr, const int* __restrict__ srcv,
    const unsigned short* __restrict__ XLb, const float* __restrict__ XR,
    const float* __restrict__ att, const float* __restrict__ bias,
    float* __restrict__ H)
{
  int node = blockIdx.x * 4 + (threadIdx.x >> 6);
  int lane = threadIdx.x & 63;
  if(node >= Nn) return;
  const float xr = XR[(size_t)node * 64 + lane];
  const float a = att[lane];
  int r0 = rowptr[node], r1 = rowptr[node + 1];
  float m[4], l[4], acc[4];
  #pragma unroll
  for(int c = 0; c < 4; c++){ m[c] = -1e30f; l[c] = 0.f; acc[c] = 0.f; }
  for(int k = r0; k < r1; k += 4){
    int nv = r1 - k;
    int s[4]; float xl[4]; float p[4];
    #pragma unroll
    for(int c = 0; c < 4; c++){
      int kk = (c < nv) ? (k + c) : k;
      s[c] = srcv[kk];
    }
    #pragma unroll
    for(int c = 0; c < 4; c++) xl[c] = bf2f(XLb[(size_t)s[c] * 64 + lane]);
    #pragma unroll
    for(int c = 0; c < 4; c++) p[c] = lrelu(xl[c] + xr) * a;
    #pragma unroll
    for(int o = 32; o; o >>= 1){
      #pragma unroll
      for(int c = 0; c < 4; c++) p[c] += __shfl_xor(p[c], o, 64);
    }
    #pragma unroll
    for(int c = 0; c < 4; c++){
      if(c < nv){
        float mn = fmaxf(m[c], p[c]);
        float sc = __expf(m[c] - mn);
        float wg = __expf(p[c] - mn);
        l[c] = l[c] * sc + wg;
        acc[c] = acc[c] * sc + wg * xl[c];
        m[c] = mn;
      }
    }
  }
  float M = fmaxf(fmaxf(m[0], m[1]), fmaxf(m[2], m[3]));
  float L = 0.f, A1 = 0.f;
  #pragma unroll
  for(int c = 0; c < 4; c++){
    float sc = __expf(m[c] - M);
    L += l[c] * sc; A1 += acc[c] * sc;
  }
  float inv = 1.f / (L + 1e-16f);
  H[(size_t)node * 64 + lane] = fmaxf(A1 * inv + bias[lane], 0.f);
}

// ---------------- fused pool + MLP head ----------------
__global__ __launch_bounds__(64) void pool_mlp(const float* __restrict__ H2,
                                               const int* __restrict__ gs,
                                               const float* __restrict__ W3,
                                               const float* __restrict__ b3,
                                               const float* __restrict__ W4,
                                               const float* __restrict__ b4,
                                               float* __restrict__ out){
  int g = blockIdx.x, t = threadIdx.x;
  int i0 = gs[g], i1 = gs[g + 1];
  float a0 = 0.f, a1 = 0.f, a2 = 0.f, a3 = 0.f;
  int i = i0;
  for(; i + 3 < i1; i += 4){
    a0 += H2[(size_t)i * 64 + t];       a1 += H2[(size_t)(i + 1) * 64 + t];
    a2 += H2[(size_t)(i + 2) * 64 + t]; a3 += H2[(size_t)(i + 3) * 64 + t];
  }
  for(; i < i1; i++) a0 += H2[(size_t)i * 64 + t];
  __shared__ float sh[64];
  sh[t] = (a0 + a1) + (a2 + a3);
  __syncthreads();
  float acc = b3[t];
  #pragma unroll
  for(int k = 0; k < 64; k++) acc = fmaf(sh[k], W3[k * 64 + t], acc);
  acc = fmaxf(acc, 0.f);
  float p = acc * W4[t];
  p = wave_sum(p);
  if(t == 0) out[g] = p + b4[0];
}

extern "C" void kernel_launch(void* const* d_in, const int* in_sizes, int n_in,
                              void* d_out, int out_size, void* d_ws, size_t ws_size,
                              hipStream_t stream)
{
  const float* x     = (const float*)d_in[0];
  const int*   ei    = (const int*)d_in[1];
  const int*   batch = (const int*)d_in[2];
  const float* Wl1   = (const float*)d_in[3];
  const float* bl1   = (const float*)d_in[4];
  const float* Wr1   = (const float*)d_in[5];
  const float* br1   = (const float*)d_in[6];
  const float* att1  = (const float*)d_in[7];
  const float* bias1 = (const float*)d_in[8];
  const float* Wl2   = (const float*)d_in[9];
  const float* bl2   = (const float*)d_in[10];
  const float* Wr2   = (const float*)d_in[11];
  const float* br2   = (const float*)d_in[12];
  const float* att2  = (const float*)d_in[13];
  const float* bias2 = (const float*)d_in[14];
  const float* W3    = (const float*)d_in[15];
  const float* b3    = (const float*)d_in[16];
  const float* W4    = (const float*)d_in[17];
  const float* b4    = (const float*)d_in[18];
  float* out = (float*)d_out;

  char* ws = (char*)d_ws;
  size_t off = 0;
  auto alloc = [&](size_t bytes) -> void* {
    void* p = ws + off;
    off += (bytes + 255) & ~(size_t)255;
    return p;
  };
  unsigned short* PA1  = (unsigned short*)alloc((size_t)NP1 * 512 * 8 * 2);      // 51.4 MB
  unsigned short* XLb1 = (unsigned short*)alloc((size_t)Nn * 256 * 2);           // 10.24 MB
  float*          XR1  = (float*)alloc((size_t)Nn * 256 * 4);                    // 20.48 MB
  unsigned short* PA2  = (unsigned short*)alloc((size_t)NTY2 * 8 * 256 * 8 * 2); // 10.3 MB
  unsigned short* XLb2 = (unsigned short*)alloc((size_t)Nn * 64 * 2);
  float*          XR2  = (float*)alloc((size_t)Nn * 64 * 4);
  unsigned short* PB1H = (unsigned short*)alloc((size_t)512 * Dd * 2);
  unsigned short* PB1L = (unsigned short*)alloc((size_t)512 * Dd * 2);
  unsigned short* PB2H = (unsigned short*)alloc((size_t)128 * 256 * 2);
  unsigned short* PB2L = (unsigned short*)alloc((size_t)128 * 256 * 2);
  int*   rowptr = (int*)alloc((size_t)(Nn + 1) * 4);
  int*   deg    = (int*)alloc((size_t)Nn * 4);
  int*   cursor = (int*)alloc((size_t)Nn * 4);
  int*   srcv   = (int*)alloc((size_t)ETOT * 4);
  float* H2   = (float*)alloc((size_t)Nn * 64 * 4);
  int*   gs   = (int*)alloc((size_t)(Gg + 1) * 4);

  const int* srcA = ei;
  const int* dstA = ei + Ee;

  hipMemsetAsync(deg, 0, (size_t)Nn * 4, stream);

  // K1: prepack X | hist | wsplit1 | wsplit2 | gbounds (independent block groups)
  k1_mega<<<K1B, 256, 0, stream>>>(x, PA1, dstA, deg,
                                   Wl1, Wr1, PB1H, PB1L,
                                   Wl2, Wr2, PB2H, PB2L,
                                   batch, gs);
  scan_deg<<<1, 1024, 0, stream>>>(deg, rowptr, cursor);

  // K2: gemm1 (pure-DMA) | scatter
  k2_gemm_scatter<<<K2B, 512, 0, stream>>>(PA1, PB1H, PB1L, bl1, br1, XLb1, XR1,
                                           srcA, dstA, cursor, srcv);
  gat_fused1<<<(Nn + 3) / 4, 256, 0, stream>>>(rowptr, srcv, XLb1, XR1, att1, bias1, PA2);

  gemm2_cp<<<NTY2, 512, 0, stream>>>(PA2, PB2H, PB2L, bl2, br2, XLb2, XR2);
  gat_fused2<<<(Nn + 3) / 4, 256, 0, stream>>>(rowptr, srcv, XLb2, XR2, att2, bias2, H2);

  pool_mlp<<<Gg, 64, 0, stream>>>(H2, gs, W3, b3, W4, b4, out);
}